// Round 4
// baseline (2508.058 us; speedup 1.0000x reference)
//
#include <hip/hip_runtime.h>
#include <stdint.h>

#define NN      100000
#define EE      1600000
#define NFEATC  128
#define NHIDC   32
#define NHEADSC 8
#define NCLASSC 40
#define FDIM    256     // NHEADS*NHID
#define QF      64      // channels per quarter
#define NQ      4

typedef unsigned short u16;

__device__ __forceinline__ float b2f(u16 u){ union{uint32_t i; float f;} v; v.i=((uint32_t)u)<<16; return v.f; }
__device__ __forceinline__ float lo2f(uint32_t u){ union{uint32_t i; float f;} v; v.i=(u<<16); return v.f; }
__device__ __forceinline__ float hi2f(uint32_t u){ union{uint32_t i; float f;} v; v.i=(u&0xFFFF0000u); return v.f; }
__device__ __forceinline__ u16 f2b(float f){ union{float f; uint32_t i;} v; v.f=f; uint32_t x=v.i; return (u16)((x + 0x7FFFu + ((x>>16)&1u))>>16); }
__device__ __forceinline__ void unpack8(uint4 v, float* f){
  f[0]=lo2f(v.x); f[1]=hi2f(v.x); f[2]=lo2f(v.y); f[3]=hi2f(v.y);
  f[4]=lo2f(v.z); f[5]=hi2f(v.z); f[6]=lo2f(v.w); f[7]=hi2f(v.w);
}

// ---------------- W transpose+cast: Wt[c][k] = bf16(W[head][k][hid]) -------
__global__ __launch_bounds__(256) void k_transposeW(const float* __restrict__ W, u16* __restrict__ Wt){
  int i = blockIdx.x*256 + threadIdx.x;
  if (i >= FDIM*NFEATC) return;
  int c = i >> 7, k = i & 127;
  int head = c >> 5, hid = c & 31;
  Wt[c*NFEATC + k] = f2b(W[head*(NFEATC*NHIDC) + k*NHIDC + hid]);
}

// ---------------- GEMM1: h0[n][c] = sum_k x[n][k] * Wt[c][k]  (bf16 out) ---
__global__ __launch_bounds__(256) void k_gemm1(const float* __restrict__ x, const u16* __restrict__ Wt,
                                               u16* __restrict__ h0){
  __shared__ float xr[NFEATC];
  int c = threadIdx.x;
  uint4 w[16];
  const uint4* wp = (const uint4*)(Wt + c*NFEATC);
  #pragma unroll
  for (int i=0;i<16;i++) w[i]=wp[i];
  int nb = blockIdx.x*32;
  for (int it=0; it<32; it++){
    int n = nb + it;
    __syncthreads();
    if (c < 32){
      float4 xv = ((const float4*)(x + (size_t)n*NFEATC))[c];
      xr[c*4+0]=xv.x; xr[c*4+1]=xv.y; xr[c*4+2]=xv.z; xr[c*4+3]=xv.w;
    }
    __syncthreads();
    float acc = 0.f;
    #pragma unroll
    for (int i=0;i<16;i++){
      float wf[8]; unpack8(w[i], wf);
      #pragma unroll
      for (int j=0;j<8;j++) acc = fmaf(xr[i*8+j], wf[j], acc);
    }
    h0[(size_t)n*FDIM + c] = f2b(acc);
  }
}

// ---------------- s,t per (node,head), bf16 --------------------------------
__global__ __launch_bounds__(256) void k_st(const u16* __restrict__ h0, const float* __restrict__ a_src,
                                            const float* __restrict__ a_dst, u16* __restrict__ s,
                                            u16* __restrict__ t_){
  int i = blockIdx.x*256 + threadIdx.x;
  if (i >= NN*NHEADSC) return;
  int n = i>>3, head = i&7;
  const u16* hp = h0 + (size_t)n*FDIM + head*NHIDC;
  const float* ap = a_src + head*NHIDC;
  const float* bp = a_dst + head*NHIDC;
  float ss=0.f, tt=0.f;
  #pragma unroll
  for (int j=0;j<NHIDC;j++){
    float h = b2f(hp[j]);
    ss = fmaf(h, ap[j], ss); tt = fmaf(h, bp[j], tt);
  }
  s[i]=f2b(ss); t_[i]=f2b(tt);
}

// ---------------- CSR build ------------------------------------------------
__global__ __launch_bounds__(256) void k_zero(int* __restrict__ p, int n){
  int i = blockIdx.x*256 + threadIdx.x;
  if (i < n) p[i] = 0;
}
__global__ __launch_bounds__(256) void k_zero_f(float* __restrict__ p, int n){
  int i = blockIdx.x*256 + threadIdx.x;
  if (i < n) p[i] = 0.f;
}
__global__ __launch_bounds__(256) void k_count(const int* __restrict__ dst, int* __restrict__ counts){
  int e = blockIdx.x*256 + threadIdx.x;
  if (e < EE) atomicAdd(&counts[dst[e]], 1);
}
__global__ __launch_bounds__(1024) void k_scan(const int* __restrict__ counts, int* __restrict__ row_start){
  __shared__ int lds[1024];
  int t = threadIdx.x;
  const int CH = 98;
  int beg = t*CH;
  int sum = 0;
  for (int i=0;i<CH;i++){ int idx=beg+i; if (idx<NN) sum += counts[idx]; }
  lds[t]=sum; __syncthreads();
  for (int off=1; off<1024; off<<=1){
    int v = (t>=off) ? lds[t-off] : 0;
    __syncthreads();
    lds[t] += v;
    __syncthreads();
  }
  int run = lds[t] - sum;
  for (int i=0;i<CH;i++){ int idx=beg+i; if (idx<NN){ row_start[idx]=run; run += counts[idx]; } }
  if (t==0) row_start[NN] = EE;
}
__global__ __launch_bounds__(256) void k_scatter(const int* __restrict__ src, const int* __restrict__ dst,
                                                 const int* __restrict__ row_start, int* __restrict__ fill,
                                                 int* __restrict__ csr_src){
  int e = blockIdx.x*256 + threadIdx.x;
  if (e >= EE) return;
  int d = dst[e];
  int pos = row_start[d] + atomicAdd(&fill[d], 1);
  csr_src[pos] = src[e];
}

// ---------------- per-(node,head): softmax max + inv-denominator ----------
__global__ __launch_bounds__(256) void k_pre(const u16* __restrict__ s, const u16* __restrict__ t_,
                                             const int* __restrict__ row_start, const int* __restrict__ csr_src,
                                             float* __restrict__ m_arr, float* __restrict__ scale){
  int i = blockIdx.x*256 + threadIdx.x;
  if (i >= NN*NHEADSC) return;
  int n = i>>3, head = i&7;
  int beg = row_start[n], end = row_start[n+1];
  float tn = b2f(t_[i]);
  float m = -1e30f;
  for (int pos=beg; pos<end; pos++){
    float e = b2f(s[csr_src[pos]*NHEADSC + head]) + tn;
    e = e > 0.f ? e : 0.2f*e;
    m = fmaxf(m, e);
  }
  if (m < -1e29f) m = 0.f;           // empty segment (mirrors reference)
  float denom = 0.f;
  for (int pos=beg; pos<end; pos++){
    float e = b2f(s[csr_src[pos]*NHEADSC + head]) + tn;
    e = e > 0.f ? e : 0.2f*e;
    denom += __expf(e - m);
  }
  m_arr[i] = m;
  scale[i] = 1.0f/(denom + 1e-16f);
}

// ---------------- hop1 (quarter): wave per node, 64 channels ---------------
__global__ __launch_bounds__(256) void k_hop1q(const u16* __restrict__ h0, const u16* __restrict__ s,
                                               const u16* __restrict__ t_, const float* __restrict__ m_arr,
                                               const float* __restrict__ scale, const int* __restrict__ row_start,
                                               const int* __restrict__ csr_src, u16* __restrict__ featAq, int q){
  int wv = threadIdx.x >> 6, l = threadIdx.x & 63;
  int n = blockIdx.x*4 + wv;
  int head = q*2 + (l>>5);
  int cg = q*QF + l;
  int ih = n*NHEADSC + head;
  float tn = b2f(t_[ih]);
  float mm = m_arr[ih];
  float sc_ = scale[ih];
  int beg = row_start[n], end = row_start[n+1];
  float acc = 0.f;
  for (int pos=beg; pos<end; pos++){
    int u = csr_src[pos];
    float e = b2f(s[u*NHEADSC + head]) + tn;
    e = e > 0.f ? e : 0.2f*e;
    float p = __expf(e - mm);
    acc = fmaf(p, b2f(h0[(size_t)u*FDIM + cg]), acc);
  }
  float res = 0.9f*sc_*acc + 0.1f*b2f(h0[(size_t)n*FDIM + cg]);
  featAq[(size_t)n*QF + l] = f2b(res);
}

// ---------------- hop2 (quarter) + elu + GEMM2 partial accumulate ----------
__global__ __launch_bounds__(256) void k_hop2q(const u16* __restrict__ featAq, const u16* __restrict__ h0,
                                               const u16* __restrict__ s, const u16* __restrict__ t_,
                                               const float* __restrict__ m_arr, const float* __restrict__ scale,
                                               const int* __restrict__ row_start, const int* __restrict__ csr_src,
                                               const float* __restrict__ W_out, float* __restrict__ out0, int q){
  __shared__ float hs[4][QF];
  int wv = threadIdx.x >> 6, l = threadIdx.x & 63;
  int n = blockIdx.x*4 + wv;
  int head = q*2 + (l>>5);
  int cg = q*QF + l;
  int ih = n*NHEADSC + head;
  float tn = b2f(t_[ih]);
  float mm = m_arr[ih];
  float sc_ = scale[ih];
  int beg = row_start[n], end = row_start[n+1];
  float acc = 0.f;
  for (int pos=beg; pos<end; pos++){
    int u = csr_src[pos];
    float e = b2f(s[u*NHEADSC + head]) + tn;
    e = e > 0.f ? e : 0.2f*e;
    float p = __expf(e - mm);
    acc = fmaf(p, b2f(featAq[(size_t)u*QF + l]), acc);
  }
  float res = 0.9f*sc_*acc + 0.1f*b2f(h0[(size_t)n*FDIM + cg]);
  hs[wv][l] = res > 0.f ? res : (__expf(res)-1.0f);   // elu per head
  __syncthreads();
  if (l < NCLASSC){
    float o = 0.f;
    #pragma unroll 8
    for (int k=0;k<QF;k++) o = fmaf(hs[wv][k], W_out[(q*QF+k)*NCLASSC + l], o);
    out0[(size_t)n*NCLASSC + l] += o;    // unique (n,l); quarters stream-serialized
  }
}

// ---------------- output-layer s,t -----------------------------------------
__global__ __launch_bounds__(256) void k_st_out(const float* __restrict__ out0, const float* __restrict__ a_s,
                                                const float* __restrict__ a_d, float* __restrict__ s,
                                                float* __restrict__ t_){
  int n = blockIdx.x*256 + threadIdx.x;
  if (n >= NN) return;
  const float* r = out0 + (size_t)n*NCLASSC;
  float ss=0.f, tt=0.f;
  for (int c=0;c<NCLASSC;c++){ float v=r[c]; ss=fmaf(v,a_s[c],ss); tt=fmaf(v,a_d[c],tt); }
  s[n]=ss; t_[n]=tt;
}

// ---------------- output-layer softmax pre-pass ----------------------------
__global__ __launch_bounds__(256) void k_pre_out(const float* __restrict__ s, const float* __restrict__ t_,
                                                 const int* __restrict__ row_start, const int* __restrict__ csr_src,
                                                 float* __restrict__ m_out, float* __restrict__ scale_out){
  int n = blockIdx.x*256 + threadIdx.x;
  if (n >= NN) return;
  int beg = row_start[n], end = row_start[n+1];
  float tn = t_[n];
  float m = -1e30f;
  for (int pos=beg; pos<end; pos++){
    float e = s[csr_src[pos]] + tn;
    e = e > 0.f ? e : 0.2f*e;
    m = fmaxf(m, e);
  }
  if (m < -1e29f) m = 0.f;
  float denom = 0.f;
  for (int pos=beg; pos<end; pos++){
    float e = s[csr_src[pos]] + tn;
    e = e > 0.f ? e : 0.2f*e;
    denom += __expf(e - m);
  }
  m_out[n] = m;
  scale_out[n] = 1.0f/(denom + 1e-16f);
}

// ---------------- output-layer hop 1 ---------------------------------------
__global__ __launch_bounds__(64) void k_hop1_out(const float* __restrict__ out0, const float* __restrict__ s,
                                                 const float* __restrict__ t_, const float* __restrict__ m_out,
                                                 const float* __restrict__ scale_out, const int* __restrict__ row_start,
                                                 const int* __restrict__ csr_src, u16* __restrict__ outA){
  int n = blockIdx.x, t = threadIdx.x;
  float tn = t_[n], mm = m_out[n], sc_ = scale_out[n];
  int beg = row_start[n], end = row_start[n+1];
  float acc = 0.f;
  for (int pos=beg; pos<end; pos++){
    int u = csr_src[pos];
    float e = s[u] + tn;
    e = e > 0.f ? e : 0.2f*e;
    float p = __expf(e - mm);
    float f = (t < NCLASSC) ? out0[(size_t)u*NCLASSC + t] : 0.f;
    acc = fmaf(p, f, acc);
  }
  if (t < NCLASSC){
    float res = 0.9f*sc_*acc + 0.1f*out0[(size_t)n*NCLASSC + t];
    outA[(size_t)n*NCLASSC + t] = f2b(res);
  }
}

// ---------------- output-layer hop 2 + elu + log_softmax (fp32 out) --------
__global__ __launch_bounds__(64) void k_hop2_out_final(const u16* __restrict__ outA, const float* __restrict__ out0,
                                                       const float* __restrict__ s, const float* __restrict__ t_,
                                                       const float* __restrict__ m_out, const float* __restrict__ scale_out,
                                                       const int* __restrict__ row_start, const int* __restrict__ csr_src,
                                                       float* __restrict__ out){
  int n = blockIdx.x, t = threadIdx.x;
  float tn = t_[n], mm = m_out[n], sc_ = scale_out[n];
  int beg = row_start[n], end = row_start[n+1];
  float acc = 0.f;
  for (int pos=beg; pos<end; pos++){
    int u = csr_src[pos];
    float e = s[u] + tn;
    e = e > 0.f ? e : 0.2f*e;
    float p = __expf(e - mm);
    float f = (t < NCLASSC) ? b2f(outA[(size_t)u*NCLASSC + t]) : 0.f;
    acc = fmaf(p, f, acc);
  }
  float v = -1e30f;
  if (t < NCLASSC){
    float res = 0.9f*sc_*acc + 0.1f*out0[(size_t)n*NCLASSC + t];
    v = res > 0.f ? res : (__expf(res)-1.0f);
  }
  float m = v;
  #pragma unroll
  for (int off=32; off; off>>=1) m = fmaxf(m, __shfl_xor(m, off));
  float ex = (t < NCLASSC) ? __expf(v - m) : 0.f;
  float ssum = ex;
  #pragma unroll
  for (int off=32; off; off>>=1) ssum += __shfl_xor(ssum, off);
  if (t < NCLASSC) out[(size_t)n*NCLASSC + t] = v - m - __logf(ssum);
}

extern "C" void kernel_launch(void* const* d_in, const int* in_sizes, int n_in,
                              void* d_out, int out_size, void* d_ws, size_t ws_size,
                              hipStream_t stream){
  const float* x        = (const float*)d_in[0];
  const int*   ei       = (const int*)d_in[1];
  const float* W        = (const float*)d_in[2];
  const float* a_src    = (const float*)d_in[3];
  const float* a_dst    = (const float*)d_in[4];
  const float* W_out    = (const float*)d_in[5];
  const float* a_src_o  = (const float*)d_in[6];
  const float* a_dst_o  = (const float*)d_in[7];
  float* out            = (float*)d_out;
  const int* e_src = ei;
  const int* e_dst = ei + EE;

  // ---- workspace: ~107 MB, no aliasing (proven-safe size) ----
  char* ws = (char*)d_ws;
  size_t off = 0;
  auto alloc = [&](size_t bytes)->char*{ char* p = ws + off; off += (bytes + 255) & ~(size_t)255; return p; };

  u16*   h0        = (u16*)  alloc((size_t)NN*FDIM*2);      // 51.2 MB
  u16*   featAq    = (u16*)  alloc((size_t)NN*QF*2);        // 12.8 MB
  float* out0      = (float*)alloc((size_t)NN*NCLASSC*4);   // 16 MB
  int*   csr_src   = (int*)  alloc((size_t)EE*4);           // 6.4 MB
  int*   row_start = (int*)  alloc((size_t)(NN+1)*4);       // 0.4 MB
  u16*   s         = (u16*)  alloc((size_t)NN*NHEADSC*2);   // 1.6 MB
  u16*   t_        = (u16*)  alloc((size_t)NN*NHEADSC*2);   // 1.6 MB
  float* m_arr     = (float*)alloc((size_t)NN*NHEADSC*4);   // 3.2 MB
  float* scale     = (float*)alloc((size_t)NN*NHEADSC*4);   // 3.2 MB
  u16*   outA      = (u16*)  alloc((size_t)NN*NCLASSC*2);   // 8 MB
  float* s_out     = (float*)alloc((size_t)NN*4);
  float* t_out     = (float*)alloc((size_t)NN*4);
  float* m_out     = (float*)alloc((size_t)NN*4);
  float* scale_out = (float*)alloc((size_t)NN*4);
  int*   counts    = (int*)  alloc((size_t)NN*4);
  u16*   Wt        = (u16*)  alloc((size_t)FDIM*NFEATC*2);

  // phase 1: feature transform + per-head s,t
  k_transposeW<<<(FDIM*NFEATC+255)/256, 256, 0, stream>>>(W, Wt);
  k_gemm1<<<NN/32, 256, 0, stream>>>(x, Wt, h0);
  k_st<<<(NN*NHEADSC+255)/256, 256, 0, stream>>>(h0, a_src, a_dst, s, t_);

  // phase 2: CSR build
  k_zero<<<(NN+255)/256, 256, 0, stream>>>(counts, NN);
  k_count<<<(EE+255)/256, 256, 0, stream>>>(e_dst, counts);
  k_scan<<<1, 1024, 0, stream>>>(counts, row_start);
  k_zero<<<(NN+255)/256, 256, 0, stream>>>(counts, NN);
  k_scatter<<<(EE+255)/256, 256, 0, stream>>>(e_src, e_dst, row_start, counts, csr_src);

  // phase 3: head attention pre-pass, then 2 hops per quarter (p on-the-fly)
  k_pre<<<(NN*NHEADSC+255)/256, 256, 0, stream>>>(s, t_, row_start, csr_src, m_arr, scale);
  k_zero_f<<<(NN*NCLASSC+255)/256, 256, 0, stream>>>(out0, NN*NCLASSC);
  for (int q=0; q<NQ; q++){
    k_hop1q<<<NN/4, 256, 0, stream>>>(h0, s, t_, m_arr, scale, row_start, csr_src, featAq, q);
    k_hop2q<<<NN/4, 256, 0, stream>>>(featAq, h0, s, t_, m_arr, scale, row_start, csr_src, W_out, out0, q);
  }

  // phase 4: output layer (p on-the-fly)
  k_st_out<<<(NN+255)/256, 256, 0, stream>>>(out0, a_src_o, a_dst_o, s_out, t_out);
  k_pre_out<<<(NN+255)/256, 256, 0, stream>>>(s_out, t_out, row_start, csr_src, m_out, scale_out);
  k_hop1_out<<<NN, 64, 0, stream>>>(out0, s_out, t_out, m_out, scale_out, row_start, csr_src, outA);
  k_hop2_out_final<<<NN, 64, 0, stream>>>(outA, out0, s_out, t_out, m_out, scale_out, row_start, csr_src, out);
}

// Round 5
// 2339.726 us; speedup vs baseline: 1.0719x; 1.0719x over previous
//
#include <hip/hip_runtime.h>
#include <stdint.h>

#define NN      100000
#define EE      1600000
#define NFEATC  128
#define NHIDC   32
#define NHEADSC 8
#define NCLASSC 40
#define FDIM    256     // NHEADS*NHID
#define QF      64      // channels per quarter
#define NQ      4

typedef unsigned short u16;

__device__ __forceinline__ float b2f(u16 u){ union{uint32_t i; float f;} v; v.i=((uint32_t)u)<<16; return v.f; }
__device__ __forceinline__ void unpack8(uint4 v, float* f){
  union{uint32_t i; float f;} c;
  c.i=v.x<<16; f[0]=c.f; c.i=v.x&0xFFFF0000u; f[1]=c.f;
  c.i=v.y<<16; f[2]=c.f; c.i=v.y&0xFFFF0000u; f[3]=c.f;
  c.i=v.z<<16; f[4]=c.f; c.i=v.z&0xFFFF0000u; f[5]=c.f;
  c.i=v.w<<16; f[6]=c.f; c.i=v.w&0xFFFF0000u; f[7]=c.f;
}
__device__ __forceinline__ u16 f2b(float f){ union{float f; uint32_t i;} v; v.f=f; uint32_t x=v.i; return (u16)((x + 0x7FFFu + ((x>>16)&1u))>>16); }

// ---------------- W transpose+cast: Wt[c][k] = bf16(W[head][k][hid]) -------
__global__ __launch_bounds__(256) void k_transposeW(const float* __restrict__ W, u16* __restrict__ Wt){
  int i = blockIdx.x*256 + threadIdx.x;
  if (i >= FDIM*NFEATC) return;
  int c = i >> 7, k = i & 127;
  int head = c >> 5, hid = c & 31;
  Wt[c*NFEATC + k] = f2b(W[head*(NFEATC*NHIDC) + k*NHIDC + hid]);
}

// ---------------- GEMM1: h0[n][c] = sum_k x[n][k] * Wt[c][k]  (bf16 out) ---
__global__ __launch_bounds__(256) void k_gemm1(const float* __restrict__ x, const u16* __restrict__ Wt,
                                               u16* __restrict__ h0){
  __shared__ float xr[NFEATC];
  int c = threadIdx.x;
  uint4 w[16];
  const uint4* wp = (const uint4*)(Wt + c*NFEATC);
  #pragma unroll
  for (int i=0;i<16;i++) w[i]=wp[i];
  int nb = blockIdx.x*32;
  for (int it=0; it<32; it++){
    int n = nb + it;
    __syncthreads();
    if (c < 32){
      float4 xv = ((const float4*)(x + (size_t)n*NFEATC))[c];
      xr[c*4+0]=xv.x; xr[c*4+1]=xv.y; xr[c*4+2]=xv.z; xr[c*4+3]=xv.w;
    }
    __syncthreads();
    float acc = 0.f;
    #pragma unroll
    for (int i=0;i<16;i++){
      float wf[8]; unpack8(w[i], wf);
      #pragma unroll
      for (int j=0;j<8;j++) acc = fmaf(xr[i*8+j], wf[j], acc);
    }
    h0[(size_t)n*FDIM + c] = f2b(acc);
  }
}

// ---------------- s,t per (node,head), bf16 --------------------------------
__global__ __launch_bounds__(256) void k_st(const u16* __restrict__ h0, const float* __restrict__ a_src,
                                            const float* __restrict__ a_dst, u16* __restrict__ s,
                                            u16* __restrict__ t_){
  int i = blockIdx.x*256 + threadIdx.x;
  if (i >= NN*NHEADSC) return;
  int n = i>>3, head = i&7;
  const u16* hp = h0 + (size_t)n*FDIM + head*NHIDC;
  const float* ap = a_src + head*NHIDC;
  const float* bp = a_dst + head*NHIDC;
  float ss=0.f, tt=0.f;
  #pragma unroll
  for (int j=0;j<NHIDC;j++){
    float h = b2f(hp[j]);
    ss = fmaf(h, ap[j], ss); tt = fmaf(h, bp[j], tt);
  }
  s[i]=f2b(ss); t_[i]=f2b(tt);
}

// ---------------- CSR build ------------------------------------------------
__global__ __launch_bounds__(256) void k_zero(int* __restrict__ p, int n){
  int i = blockIdx.x*256 + threadIdx.x;
  if (i < n) p[i] = 0;
}
__global__ __launch_bounds__(256) void k_zero_f(float* __restrict__ p, int n){
  int i = blockIdx.x*256 + threadIdx.x;
  if (i < n) p[i] = 0.f;
}
__global__ __launch_bounds__(256) void k_count(const int* __restrict__ dst, int* __restrict__ counts){
  int e = blockIdx.x*256 + threadIdx.x;
  if (e < EE) atomicAdd(&counts[dst[e]], 1);
}
__global__ __launch_bounds__(1024) void k_scan(const int* __restrict__ counts, int* __restrict__ row_start){
  __shared__ int lds[1024];
  int t = threadIdx.x;
  const int CH = 98;
  int beg = t*CH;
  int sum = 0;
  for (int i=0;i<CH;i++){ int idx=beg+i; if (idx<NN) sum += counts[idx]; }
  lds[t]=sum; __syncthreads();
  for (int off=1; off<1024; off<<=1){
    int v = (t>=off) ? lds[t-off] : 0;
    __syncthreads();
    lds[t] += v;
    __syncthreads();
  }
  int run = lds[t] - sum;
  for (int i=0;i<CH;i++){ int idx=beg+i; if (idx<NN){ row_start[idx]=run; run += counts[idx]; } }
  if (t==0) row_start[NN] = EE;
}
__global__ __launch_bounds__(256) void k_scatter(const int* __restrict__ src, const int* __restrict__ dst,
                                                 const int* __restrict__ row_start, int* __restrict__ fill,
                                                 int* __restrict__ csr_src){
  int e = blockIdx.x*256 + threadIdx.x;
  if (e >= EE) return;
  int d = dst[e];
  int pos = row_start[d] + atomicAdd(&fill[d], 1);
  csr_src[pos] = src[e];
}

// ---------------- per-quarter attention: p (bf16) + inv-denominator --------
// heads {2q, 2q+1}; single pass, no max-shift (|e| <~ 6, exp-safe; shift
// cancels in softmax). denom accumulated from ROUNDED p for self-consistency.
__global__ __launch_bounds__(256) void k_attq(const u16* __restrict__ s, const u16* __restrict__ t_,
                                              const int* __restrict__ row_start, const int* __restrict__ csr_src,
                                              u16* __restrict__ p_wq, float* __restrict__ scale, int q){
  int i = blockIdx.x*256 + threadIdx.x;
  if (i >= NN*2) return;
  int n = i>>1, hh = i&1, head = q*2 + hh;
  int beg = row_start[n], end = row_start[n+1];
  float tn = b2f(t_[n*NHEADSC + head]);
  float denom = 0.f;
  for (int pos=beg; pos<end; pos++){
    float e = b2f(s[csr_src[pos]*NHEADSC + head]) + tn;
    e = e > 0.f ? e : 0.2f*e;
    u16 pb = f2b(__expf(e));
    p_wq[pos*2 + hh] = pb;
    denom += b2f(pb);
  }
  scale[n*NHEADSC + head] = 1.0f/(denom + 1e-16f);
}

// ---------------- hop1 (quarter): wave per node, 64 channels ---------------
__global__ __launch_bounds__(256) void k_hop1q(const u16* __restrict__ h0, const u16* __restrict__ p_wq,
                                               const float* __restrict__ scale, const int* __restrict__ row_start,
                                               const int* __restrict__ csr_src, u16* __restrict__ featAq, int q){
  int wv = threadIdx.x >> 6, l = threadIdx.x & 63;
  int n = blockIdx.x*4 + wv;
  int hh = l>>5;
  int cg = q*QF + l;
  float sc_ = scale[n*NHEADSC + q*2 + hh];
  int beg = row_start[n], end = row_start[n+1];
  float acc = 0.f;
  for (int pos=beg; pos<end; pos++){
    int u = csr_src[pos];
    float p = b2f(p_wq[pos*2 + hh]);
    acc = fmaf(p, b2f(h0[(size_t)u*FDIM + cg]), acc);
  }
  float res = 0.9f*sc_*acc + 0.1f*b2f(h0[(size_t)n*FDIM + cg]);
  featAq[(size_t)n*QF + l] = f2b(res);
}

// ---------------- hop2 (quarter) + elu + GEMM2 partial accumulate ----------
__global__ __launch_bounds__(256) void k_hop2q(const u16* __restrict__ featAq, const u16* __restrict__ h0,
                                               const u16* __restrict__ p_wq, const float* __restrict__ scale,
                                               const int* __restrict__ row_start, const int* __restrict__ csr_src,
                                               const float* __restrict__ W_out, float* __restrict__ out0, int q){
  __shared__ float hs[4][QF];
  int wv = threadIdx.x >> 6, l = threadIdx.x & 63;
  int n = blockIdx.x*4 + wv;
  int hh = l>>5;
  int cg = q*QF + l;
  float sc_ = scale[n*NHEADSC + q*2 + hh];
  int beg = row_start[n], end = row_start[n+1];
  float acc = 0.f;
  for (int pos=beg; pos<end; pos++){
    int u = csr_src[pos];
    float p = b2f(p_wq[pos*2 + hh]);
    acc = fmaf(p, b2f(featAq[(size_t)u*QF + l]), acc);
  }
  float res = 0.9f*sc_*acc + 0.1f*b2f(h0[(size_t)n*FDIM + cg]);
  hs[wv][l] = res > 0.f ? res : (__expf(res)-1.0f);   // elu per head
  __syncthreads();
  if (l < NCLASSC){
    float o = 0.f;
    #pragma unroll 8
    for (int k=0;k<QF;k++) o = fmaf(hs[wv][k], W_out[(q*QF+k)*NCLASSC + l], o);
    out0[(size_t)n*NCLASSC + l] += o;    // unique (n,l); quarters stream-serialized
  }
}

// ---------------- output-layer s,t -----------------------------------------
__global__ __launch_bounds__(256) void k_st_out(const float* __restrict__ out0, const float* __restrict__ a_s,
                                                const float* __restrict__ a_d, float* __restrict__ s,
                                                float* __restrict__ t_){
  int n = blockIdx.x*256 + threadIdx.x;
  if (n >= NN) return;
  const float* r = out0 + (size_t)n*NCLASSC;
  float ss=0.f, tt=0.f;
  for (int c=0;c<NCLASSC;c++){ float v=r[c]; ss=fmaf(v,a_s[c],ss); tt=fmaf(v,a_d[c],tt); }
  s[n]=ss; t_[n]=tt;
}

// ---------------- output-layer attention: p (fp32) + inv-denominator -------
__global__ __launch_bounds__(256) void k_att_out(const float* __restrict__ s, const float* __restrict__ t_,
                                                 const int* __restrict__ row_start, const int* __restrict__ csr_src,
                                                 float* __restrict__ p_out, float* __restrict__ scale_out){
  int n = blockIdx.x*256 + threadIdx.x;
  if (n >= NN) return;
  int beg = row_start[n], end = row_start[n+1];
  float tn = t_[n];
  float denom = 0.f;
  for (int pos=beg; pos<end; pos++){
    float e = s[csr_src[pos]] + tn;
    e = e > 0.f ? e : 0.2f*e;
    float p = __expf(e);
    p_out[pos] = p;
    denom += p;
  }
  scale_out[n] = 1.0f/(denom + 1e-16f);
}

// ---------------- output-layer hop 1 ---------------------------------------
__global__ __launch_bounds__(64) void k_hop1_out(const float* __restrict__ out0, const float* __restrict__ p_out,
                                                 const float* __restrict__ scale_out, const int* __restrict__ row_start,
                                                 const int* __restrict__ csr_src, u16* __restrict__ outA){
  int n = blockIdx.x, t = threadIdx.x;
  float sc_ = scale_out[n];
  int beg = row_start[n], end = row_start[n+1];
  float acc = 0.f;
  for (int pos=beg; pos<end; pos++){
    int u = csr_src[pos];
    float p = p_out[pos];
    float f = (t < NCLASSC) ? out0[(size_t)u*NCLASSC + t] : 0.f;
    acc = fmaf(p, f, acc);
  }
  if (t < NCLASSC){
    float res = 0.9f*sc_*acc + 0.1f*out0[(size_t)n*NCLASSC + t];
    outA[(size_t)n*NCLASSC + t] = f2b(res);
  }
}

// ---------------- output-layer hop 2 + elu + log_softmax (fp32 out) --------
__global__ __launch_bounds__(64) void k_hop2_out_final(const u16* __restrict__ outA, const float* __restrict__ out0,
                                                       const float* __restrict__ p_out, const float* __restrict__ scale_out,
                                                       const int* __restrict__ row_start, const int* __restrict__ csr_src,
                                                       float* __restrict__ out){
  int n = blockIdx.x, t = threadIdx.x;
  float sc_ = scale_out[n];
  int beg = row_start[n], end = row_start[n+1];
  float acc = 0.f;
  for (int pos=beg; pos<end; pos++){
    int u = csr_src[pos];
    float p = p_out[pos];
    float f = (t < NCLASSC) ? b2f(outA[(size_t)u*NCLASSC + t]) : 0.f;
    acc = fmaf(p, f, acc);
  }
  float v = -1e30f;
  if (t < NCLASSC){
    float res = 0.9f*sc_*acc + 0.1f*out0[(size_t)n*NCLASSC + t];
    v = res > 0.f ? res : (__expf(res)-1.0f);
  }
  float m = v;
  #pragma unroll
  for (int off=32; off; off>>=1) m = fmaxf(m, __shfl_xor(m, off));
  float ex = (t < NCLASSC) ? __expf(v - m) : 0.f;
  float ssum = ex;
  #pragma unroll
  for (int off=32; off; off>>=1) ssum += __shfl_xor(ssum, off);
  if (t < NCLASSC) out[(size_t)n*NCLASSC + t] = v - m - __logf(ssum);
}

extern "C" void kernel_launch(void* const* d_in, const int* in_sizes, int n_in,
                              void* d_out, int out_size, void* d_ws, size_t ws_size,
                              hipStream_t stream){
  const float* x        = (const float*)d_in[0];
  const int*   ei       = (const int*)d_in[1];
  const float* W        = (const float*)d_in[2];
  const float* a_src    = (const float*)d_in[3];
  const float* a_dst    = (const float*)d_in[4];
  const float* W_out    = (const float*)d_in[5];
  const float* a_src_o  = (const float*)d_in[6];
  const float* a_dst_o  = (const float*)d_in[7];
  float* out            = (float*)d_out;
  const int* e_src = ei;
  const int* e_dst = ei + EE;

  // ---- workspace: ~109 MB ----
  char* ws = (char*)d_ws;
  size_t off = 0;
  auto alloc = [&](size_t bytes)->char*{ char* p = ws + off; off += (bytes + 255) & ~(size_t)255; return p; };

  u16*   h0        = (u16*)  alloc((size_t)NN*FDIM*2);      // 51.2 MB
  u16*   featAq    = (u16*)  alloc((size_t)NN*QF*2);        // 12.8 MB
  float* out0      = (float*)alloc((size_t)NN*NCLASSC*4);   // 16 MB
  int*   csr_src   = (int*)  alloc((size_t)EE*4);           // 6.4 MB
  int*   row_start = (int*)  alloc((size_t)(NN+1)*4);       // 0.4 MB
  u16*   s         = (u16*)  alloc((size_t)NN*NHEADSC*2);   // 1.6 MB
  u16*   t_        = (u16*)  alloc((size_t)NN*NHEADSC*2);   // 1.6 MB
  u16*   p_wq      = (u16*)  alloc((size_t)EE*2*2);         // 6.4 MB (phase 3; fp32 p_out in phase 4)
  float* scale     = (float*)alloc((size_t)NN*NHEADSC*4);   // 3.2 MB
  u16*   outA      = (u16*)  alloc((size_t)NN*NCLASSC*2);   // 8 MB
  float* s_out     = (float*)alloc((size_t)NN*4);
  float* t_out     = (float*)alloc((size_t)NN*4);
  float* scale_out = (float*)alloc((size_t)NN*4);
  int*   counts    = (int*)  alloc((size_t)NN*4);
  u16*   Wt        = (u16*)  alloc((size_t)FDIM*NFEATC*2);
  float* p_out     = (float*)p_wq;                          // alias: p_wq dead after phase 3

  // phase 1: feature transform + per-head s,t
  k_transposeW<<<(FDIM*NFEATC+255)/256, 256, 0, stream>>>(W, Wt);
  k_gemm1<<<NN/32, 256, 0, stream>>>(x, Wt, h0);
  k_st<<<(NN*NHEADSC+255)/256, 256, 0, stream>>>(h0, a_src, a_dst, s, t_);

  // phase 2: CSR build
  k_zero<<<(NN+255)/256, 256, 0, stream>>>(counts, NN);
  k_count<<<(EE+255)/256, 256, 0, stream>>>(e_dst, counts);
  k_scan<<<1, 1024, 0, stream>>>(counts, row_start);
  k_zero<<<(NN+255)/256, 256, 0, stream>>>(counts, NN);
  k_scatter<<<(EE+255)/256, 256, 0, stream>>>(e_src, e_dst, row_start, counts, csr_src);

  // phase 3: per quarter: attention p pre-pass, then 2 hops reading p
  k_zero_f<<<(NN*NCLASSC+255)/256, 256, 0, stream>>>(out0, NN*NCLASSC);
  for (int q=0; q<NQ; q++){
    k_attq<<<(NN*2+255)/256, 256, 0, stream>>>(s, t_, row_start, csr_src, p_wq, scale, q);
    k_hop1q<<<NN/4, 256, 0, stream>>>(h0, p_wq, scale, row_start, csr_src, featAq, q);
    k_hop2q<<<NN/4, 256, 0, stream>>>(featAq, h0, p_wq, scale, row_start, csr_src, W_out, out0, q);
  }

  // phase 4: output layer (p precomputed, fp32, aliased into p_wq)
  k_st_out<<<(NN+255)/256, 256, 0, stream>>>(out0, a_src_o, a_dst_o, s_out, t_out);
  k_att_out<<<(NN+255)/256, 256, 0, stream>>>(s_out, t_out, row_start, csr_src, p_out, scale_out);
  k_hop1_out<<<NN, 64, 0, stream>>>(out0, p_out, scale_out, row_start, csr_src, outA);
  k_hop2_out_final<<<NN, 64, 0, stream>>>(outA, out0, p_out, scale_out, row_start, csr_src, out);
}

// Round 6
// 1728.751 us; speedup vs baseline: 1.4508x; 1.3534x over previous
//
#include <hip/hip_runtime.h>
#include <stdint.h>

#define NN      100000
#define EE      1600000
#define NFEATC  128
#define NHIDC   32
#define NHEADSC 8
#define NCLASSC 40
#define FDIM    256     // NHEADS*NHID
#define QF      64      // channels per quarter
#define NQ      4

typedef unsigned short u16;

__device__ __forceinline__ float b2f(u16 u){ union{uint32_t i; float f;} v; v.i=((uint32_t)u)<<16; return v.f; }
__device__ __forceinline__ void unpack8(uint4 v, float* f){
  union{uint32_t i; float f;} c;
  c.i=v.x<<16; f[0]=c.f; c.i=v.x&0xFFFF0000u; f[1]=c.f;
  c.i=v.y<<16; f[2]=c.f; c.i=v.y&0xFFFF0000u; f[3]=c.f;
  c.i=v.z<<16; f[4]=c.f; c.i=v.z&0xFFFF0000u; f[5]=c.f;
  c.i=v.w<<16; f[6]=c.f; c.i=v.w&0xFFFF0000u; f[7]=c.f;
}
__device__ __forceinline__ u16 f2b(float f){ union{float f; uint32_t i;} v; v.f=f; uint32_t x=v.i; return (u16)((x + 0x7FFFu + ((x>>16)&1u))>>16); }
__device__ __forceinline__ float lrelu(float e){ return e > 0.f ? e : 0.2f*e; }

// ---------------- W transpose+cast: Wt[c][k] = bf16(W[head][k][hid]) -------
__global__ __launch_bounds__(256) void k_transposeW(const float* __restrict__ W, u16* __restrict__ Wt){
  int i = blockIdx.x*256 + threadIdx.x;
  if (i >= FDIM*NFEATC) return;
  int c = i >> 7, k = i & 127;
  int head = c >> 5, hid = c & 31;
  Wt[c*NFEATC + k] = f2b(W[head*(NFEATC*NHIDC) + k*NHIDC + hid]);
}

// ---------------- GEMM1: h0[n][c] = sum_k x[n][k] * Wt[c][k]  (bf16 out) ---
// one-shot staging of 32 node rows (16 KB LDS), single barrier
__global__ __launch_bounds__(256) void k_gemm1(const float* __restrict__ x, const u16* __restrict__ Wt,
                                               u16* __restrict__ h0){
  __shared__ float xr[32*NFEATC];   // 16 KB
  int c = threadIdx.x;
  uint4 w[16];
  const uint4* wp = (const uint4*)(Wt + c*NFEATC);
  #pragma unroll
  for (int i=0;i<16;i++) w[i]=wp[i];
  int nb = blockIdx.x*32;
  const float4* xs = (const float4*)(x + (size_t)nb*NFEATC);
  float4* xd = (float4*)xr;
  #pragma unroll
  for (int i=0;i<4;i++) xd[c + 256*i] = xs[c + 256*i];
  __syncthreads();
  for (int it=0; it<32; it++){
    const float* row = xr + it*NFEATC;
    float acc = 0.f;
    #pragma unroll
    for (int i=0;i<16;i++){
      float wf[8]; unpack8(w[i], wf);
      #pragma unroll
      for (int j=0;j<8;j++) acc = fmaf(row[i*8+j], wf[j], acc);
    }
    h0[(size_t)(nb+it)*FDIM + c] = f2b(acc);
  }
}

// ---------------- s,t per (node,head), bf16 --------------------------------
__global__ __launch_bounds__(256) void k_st(const u16* __restrict__ h0, const float* __restrict__ a_src,
                                            const float* __restrict__ a_dst, u16* __restrict__ s,
                                            u16* __restrict__ t_){
  int i = blockIdx.x*256 + threadIdx.x;
  if (i >= NN*NHEADSC) return;
  int n = i>>3, head = i&7;
  const u16* hp = h0 + (size_t)n*FDIM + head*NHIDC;
  const float* ap = a_src + head*NHIDC;
  const float* bp = a_dst + head*NHIDC;
  float ss=0.f, tt=0.f;
  #pragma unroll
  for (int j=0;j<NHIDC;j++){
    float h = b2f(hp[j]);
    ss = fmaf(h, ap[j], ss); tt = fmaf(h, bp[j], tt);
  }
  s[i]=f2b(ss); t_[i]=f2b(tt);
}

// ---------------- CSR build ------------------------------------------------
__global__ __launch_bounds__(256) void k_zero(int* __restrict__ p, int n){
  int i = blockIdx.x*256 + threadIdx.x;
  if (i < n) p[i] = 0;
}
__global__ __launch_bounds__(256) void k_zero_f(float* __restrict__ p, int n){
  int i = blockIdx.x*256 + threadIdx.x;
  if (i < n) p[i] = 0.f;
}
__global__ __launch_bounds__(256) void k_count(const int* __restrict__ dst, int* __restrict__ counts){
  int e = blockIdx.x*256 + threadIdx.x;
  if (e < EE) atomicAdd(&counts[dst[e]], 1);
}
__global__ __launch_bounds__(1024) void k_scan(const int* __restrict__ counts, int* __restrict__ row_start){
  __shared__ int lds[1024];
  int t = threadIdx.x;
  const int CH = 98;
  int beg = t*CH;
  int sum = 0;
  for (int i=0;i<CH;i++){ int idx=beg+i; if (idx<NN) sum += counts[idx]; }
  lds[t]=sum; __syncthreads();
  for (int off=1; off<1024; off<<=1){
    int v = (t>=off) ? lds[t-off] : 0;
    __syncthreads();
    lds[t] += v;
    __syncthreads();
  }
  int run = lds[t] - sum;
  for (int i=0;i<CH;i++){ int idx=beg+i; if (idx<NN){ row_start[idx]=run; run += counts[idx]; } }
  if (t==0) row_start[NN] = EE;
}
__global__ __launch_bounds__(256) void k_scatter(const int* __restrict__ src, const int* __restrict__ dst,
                                                 const int* __restrict__ row_start, int* __restrict__ fill,
                                                 int* __restrict__ csr_src){
  int e = blockIdx.x*256 + threadIdx.x;
  if (e >= EE) return;
  int d = dst[e];
  int pos = row_start[d] + atomicAdd(&fill[d], 1);
  csr_src[pos] = src[e];
}

// ---------------- attention, all 8 heads: p_all (bf16) + inv-denominator ---
// single pass, no max-shift (|e| small; shift cancels in softmax).
// denom accumulated from ROUNDED p for self-consistency. unroll x4 for MLP.
__global__ __launch_bounds__(256) void k_att(const u16* __restrict__ s, const u16* __restrict__ t_,
                                             const int* __restrict__ row_start, const int* __restrict__ csr_src,
                                             u16* __restrict__ p_all, float* __restrict__ scale){
  int i = blockIdx.x*256 + threadIdx.x;
  if (i >= NN*NHEADSC) return;
  int n = i>>3, head = i&7;
  int beg = row_start[n], end = row_start[n+1];
  float tn = b2f(t_[i]);
  float d0=0.f,d1=0.f,d2=0.f,d3=0.f;
  int pos = beg;
  for (; pos+4<=end; pos+=4){
    int u0=csr_src[pos], u1=csr_src[pos+1], u2=csr_src[pos+2], u3=csr_src[pos+3];
    float e0=lrelu(b2f(s[u0*NHEADSC+head])+tn);
    float e1=lrelu(b2f(s[u1*NHEADSC+head])+tn);
    float e2=lrelu(b2f(s[u2*NHEADSC+head])+tn);
    float e3=lrelu(b2f(s[u3*NHEADSC+head])+tn);
    u16 p0=f2b(__expf(e0)), p1=f2b(__expf(e1)), p2=f2b(__expf(e2)), p3=f2b(__expf(e3));
    p_all[(size_t)(pos+0)*NHEADSC+head]=p0;
    p_all[(size_t)(pos+1)*NHEADSC+head]=p1;
    p_all[(size_t)(pos+2)*NHEADSC+head]=p2;
    p_all[(size_t)(pos+3)*NHEADSC+head]=p3;
    d0+=b2f(p0); d1+=b2f(p1); d2+=b2f(p2); d3+=b2f(p3);
  }
  for (; pos<end; pos++){
    int u = csr_src[pos];
    float e = lrelu(b2f(s[u*NHEADSC+head])+tn);
    u16 pb = f2b(__expf(e));
    p_all[(size_t)pos*NHEADSC+head]=pb;
    d0 += b2f(pb);
  }
  scale[i] = 1.0f/(((d0+d1)+(d2+d3)) + 1e-16f);
}

// ---------------- hop1 (quarter): wave per node, 64 channels, unroll x4 ----
__global__ __launch_bounds__(256) void k_hop1q(const u16* __restrict__ h0, const u16* __restrict__ p_all,
                                               const float* __restrict__ scale, const int* __restrict__ row_start,
                                               const int* __restrict__ csr_src, u16* __restrict__ featAq, int q){
  int wv = threadIdx.x >> 6, l = threadIdx.x & 63;
  int n = blockIdx.x*4 + wv;
  int head = q*2 + (l>>5);
  int cg = q*QF + l;
  float sc_ = scale[n*NHEADSC + head];
  int beg = row_start[n], end = row_start[n+1];
  float a0=0.f,a1=0.f,a2=0.f,a3=0.f;
  int pos = beg;
  for (; pos+4<=end; pos+=4){
    int u0=csr_src[pos], u1=csr_src[pos+1], u2=csr_src[pos+2], u3=csr_src[pos+3];
    float p0=b2f(p_all[(size_t)(pos+0)*NHEADSC+head]);
    float p1=b2f(p_all[(size_t)(pos+1)*NHEADSC+head]);
    float p2=b2f(p_all[(size_t)(pos+2)*NHEADSC+head]);
    float p3=b2f(p_all[(size_t)(pos+3)*NHEADSC+head]);
    float g0=b2f(h0[(size_t)u0*FDIM+cg]);
    float g1=b2f(h0[(size_t)u1*FDIM+cg]);
    float g2=b2f(h0[(size_t)u2*FDIM+cg]);
    float g3=b2f(h0[(size_t)u3*FDIM+cg]);
    a0=fmaf(p0,g0,a0); a1=fmaf(p1,g1,a1); a2=fmaf(p2,g2,a2); a3=fmaf(p3,g3,a3);
  }
  for (; pos<end; pos++){
    int u=csr_src[pos];
    a0=fmaf(b2f(p_all[(size_t)pos*NHEADSC+head]), b2f(h0[(size_t)u*FDIM+cg]), a0);
  }
  float acc=(a0+a1)+(a2+a3);
  float res = 0.9f*sc_*acc + 0.1f*b2f(h0[(size_t)n*FDIM + cg]);
  featAq[(size_t)n*QF + l] = f2b(res);
}

// ---------------- hop2 (quarter) + elu + GEMM2 partial, unroll x4 ----------
__global__ __launch_bounds__(256) void k_hop2q(const u16* __restrict__ featAq, const u16* __restrict__ h0,
                                               const u16* __restrict__ p_all, const float* __restrict__ scale,
                                               const int* __restrict__ row_start, const int* __restrict__ csr_src,
                                               const float* __restrict__ W_out, float* __restrict__ out0, int q){
  __shared__ float hs[4][QF];
  int wv = threadIdx.x >> 6, l = threadIdx.x & 63;
  int n = blockIdx.x*4 + wv;
  int head = q*2 + (l>>5);
  int cg = q*QF + l;
  float sc_ = scale[n*NHEADSC + head];
  int beg = row_start[n], end = row_start[n+1];
  float a0=0.f,a1=0.f,a2=0.f,a3=0.f;
  int pos = beg;
  for (; pos+4<=end; pos+=4){
    int u0=csr_src[pos], u1=csr_src[pos+1], u2=csr_src[pos+2], u3=csr_src[pos+3];
    float p0=b2f(p_all[(size_t)(pos+0)*NHEADSC+head]);
    float p1=b2f(p_all[(size_t)(pos+1)*NHEADSC+head]);
    float p2=b2f(p_all[(size_t)(pos+2)*NHEADSC+head]);
    float p3=b2f(p_all[(size_t)(pos+3)*NHEADSC+head]);
    float g0=b2f(featAq[(size_t)u0*QF+l]);
    float g1=b2f(featAq[(size_t)u1*QF+l]);
    float g2=b2f(featAq[(size_t)u2*QF+l]);
    float g3=b2f(featAq[(size_t)u3*QF+l]);
    a0=fmaf(p0,g0,a0); a1=fmaf(p1,g1,a1); a2=fmaf(p2,g2,a2); a3=fmaf(p3,g3,a3);
  }
  for (; pos<end; pos++){
    int u=csr_src[pos];
    a0=fmaf(b2f(p_all[(size_t)pos*NHEADSC+head]), b2f(featAq[(size_t)u*QF+l]), a0);
  }
  float acc=(a0+a1)+(a2+a3);
  float res = 0.9f*sc_*acc + 0.1f*b2f(h0[(size_t)n*FDIM + cg]);
  hs[wv][l] = res > 0.f ? res : (__expf(res)-1.0f);   // elu per head
  __syncthreads();
  if (l < NCLASSC){
    float o = 0.f;
    #pragma unroll 8
    for (int k=0;k<QF;k++) o = fmaf(hs[wv][k], W_out[(q*QF+k)*NCLASSC + l], o);
    out0[(size_t)n*NCLASSC + l] += o;    // unique (n,l); quarters stream-serialized
  }
}

// ---------------- output-layer s,t -----------------------------------------
__global__ __launch_bounds__(256) void k_st_out(const float* __restrict__ out0, const float* __restrict__ a_s,
                                                const float* __restrict__ a_d, float* __restrict__ s,
                                                float* __restrict__ t_){
  int n = blockIdx.x*256 + threadIdx.x;
  if (n >= NN) return;
  const float* r = out0 + (size_t)n*NCLASSC;
  float ss=0.f, tt=0.f;
  for (int c=0;c<NCLASSC;c++){ float v=r[c]; ss=fmaf(v,a_s[c],ss); tt=fmaf(v,a_d[c],tt); }
  s[n]=ss; t_[n]=tt;
}

// ---------------- output-layer attention: p (fp32), unroll x4 --------------
__global__ __launch_bounds__(256) void k_att_out(const float* __restrict__ s, const float* __restrict__ t_,
                                                 const int* __restrict__ row_start, const int* __restrict__ csr_src,
                                                 float* __restrict__ p_out, float* __restrict__ scale_out){
  int n = blockIdx.x*256 + threadIdx.x;
  if (n >= NN) return;
  int beg = row_start[n], end = row_start[n+1];
  float tn = t_[n];
  float d0=0.f,d1=0.f,d2=0.f,d3=0.f;
  int pos = beg;
  for (; pos+4<=end; pos+=4){
    int u0=csr_src[pos], u1=csr_src[pos+1], u2=csr_src[pos+2], u3=csr_src[pos+3];
    float p0=__expf(lrelu(s[u0]+tn));
    float p1=__expf(lrelu(s[u1]+tn));
    float p2=__expf(lrelu(s[u2]+tn));
    float p3=__expf(lrelu(s[u3]+tn));
    p_out[pos]=p0; p_out[pos+1]=p1; p_out[pos+2]=p2; p_out[pos+3]=p3;
    d0+=p0; d1+=p1; d2+=p2; d3+=p3;
  }
  for (; pos<end; pos++){
    float p = __expf(lrelu(s[csr_src[pos]]+tn));
    p_out[pos] = p;
    d0 += p;
  }
  scale_out[n] = 1.0f/(((d0+d1)+(d2+d3)) + 1e-16f);
}

// ---------------- output-layer hop 1, unroll x4 ----------------------------
__global__ __launch_bounds__(64) void k_hop1_out(const float* __restrict__ out0, const float* __restrict__ p_out,
                                                 const float* __restrict__ scale_out, const int* __restrict__ row_start,
                                                 const int* __restrict__ csr_src, u16* __restrict__ outA){
  int n = blockIdx.x, t = threadIdx.x;
  float sc_ = scale_out[n];
  int beg = row_start[n], end = row_start[n+1];
  int tc = (t < NCLASSC) ? t : 0;
  float a0=0.f,a1=0.f,a2=0.f,a3=0.f;
  int pos = beg;
  for (; pos+4<=end; pos+=4){
    int u0=csr_src[pos], u1=csr_src[pos+1], u2=csr_src[pos+2], u3=csr_src[pos+3];
    float p0=p_out[pos], p1=p_out[pos+1], p2=p_out[pos+2], p3=p_out[pos+3];
    float f0=out0[(size_t)u0*NCLASSC+tc];
    float f1=out0[(size_t)u1*NCLASSC+tc];
    float f2=out0[(size_t)u2*NCLASSC+tc];
    float f3=out0[(size_t)u3*NCLASSC+tc];
    a0=fmaf(p0,f0,a0); a1=fmaf(p1,f1,a1); a2=fmaf(p2,f2,a2); a3=fmaf(p3,f3,a3);
  }
  for (; pos<end; pos++){
    a0=fmaf(p_out[pos], out0[(size_t)csr_src[pos]*NCLASSC+tc], a0);
  }
  if (t < NCLASSC){
    float res = 0.9f*sc_*((a0+a1)+(a2+a3)) + 0.1f*out0[(size_t)n*NCLASSC + t];
    outA[(size_t)n*NCLASSC + t] = f2b(res);
  }
}

// ---------------- output-layer hop 2 + elu + log_softmax, unroll x4 --------
__global__ __launch_bounds__(64) void k_hop2_out_final(const u16* __restrict__ outA, const float* __restrict__ out0,
                                                       const float* __restrict__ p_out, const float* __restrict__ scale_out,
                                                       const int* __restrict__ row_start, const int* __restrict__ csr_src,
                                                       float* __restrict__ out){
  int n = blockIdx.x, t = threadIdx.x;
  float sc_ = scale_out[n];
  int beg = row_start[n], end = row_start[n+1];
  int tc = (t < NCLASSC) ? t : 0;
  float a0=0.f,a1=0.f,a2=0.f,a3=0.f;
  int pos = beg;
  for (; pos+4<=end; pos+=4){
    int u0=csr_src[pos], u1=csr_src[pos+1], u2=csr_src[pos+2], u3=csr_src[pos+3];
    float p0=p_out[pos], p1=p_out[pos+1], p2=p_out[pos+2], p3=p_out[pos+3];
    float f0=b2f(outA[(size_t)u0*NCLASSC+tc]);
    float f1=b2f(outA[(size_t)u1*NCLASSC+tc]);
    float f2=b2f(outA[(size_t)u2*NCLASSC+tc]);
    float f3=b2f(outA[(size_t)u3*NCLASSC+tc]);
    a0=fmaf(p0,f0,a0); a1=fmaf(p1,f1,a1); a2=fmaf(p2,f2,a2); a3=fmaf(p3,f3,a3);
  }
  for (; pos<end; pos++){
    a0=fmaf(p_out[pos], b2f(outA[(size_t)csr_src[pos]*NCLASSC+tc]), a0);
  }
  float v = -1e30f;
  if (t < NCLASSC){
    float res = 0.9f*sc_*((a0+a1)+(a2+a3)) + 0.1f*out0[(size_t)n*NCLASSC + t];
    v = res > 0.f ? res : (__expf(res)-1.0f);
  }
  float m = v;
  #pragma unroll
  for (int off=32; off; off>>=1) m = fmaxf(m, __shfl_xor(m, off));
  float ex = (t < NCLASSC) ? __expf(v - m) : 0.f;
  float ssum = ex;
  #pragma unroll
  for (int off=32; off; off>>=1) ssum += __shfl_xor(ssum, off);
  if (t < NCLASSC) out[(size_t)n*NCLASSC + t] = v - m - __logf(ssum);
}

extern "C" void kernel_launch(void* const* d_in, const int* in_sizes, int n_in,
                              void* d_out, int out_size, void* d_ws, size_t ws_size,
                              hipStream_t stream){
  const float* x        = (const float*)d_in[0];
  const int*   ei       = (const int*)d_in[1];
  const float* W        = (const float*)d_in[2];
  const float* a_src    = (const float*)d_in[3];
  const float* a_dst    = (const float*)d_in[4];
  const float* W_out    = (const float*)d_in[5];
  const float* a_src_o  = (const float*)d_in[6];
  const float* a_dst_o  = (const float*)d_in[7];
  float* out            = (float*)d_out;
  const int* e_src = ei;
  const int* e_dst = ei + EE;

  // ---- workspace: ~129 MB (<=157 MB proven safe) ----
  char* ws = (char*)d_ws;
  size_t off = 0;
  auto alloc = [&](size_t bytes)->char*{ char* p = ws + off; off += (bytes + 255) & ~(size_t)255; return p; };

  u16*   h0        = (u16*)  alloc((size_t)NN*FDIM*2);      // 51.2 MB
  u16*   featAq    = (u16*)  alloc((size_t)NN*QF*2);        // 12.8 MB
  float* out0      = (float*)alloc((size_t)NN*NCLASSC*4);   // 16 MB
  int*   csr_src   = (int*)  alloc((size_t)EE*4);           // 6.4 MB
  int*   row_start = (int*)  alloc((size_t)(NN+1)*4);       // 0.4 MB
  u16*   s         = (u16*)  alloc((size_t)NN*NHEADSC*2);   // 1.6 MB
  u16*   t_        = (u16*)  alloc((size_t)NN*NHEADSC*2);   // 1.6 MB
  u16*   p_all     = (u16*)  alloc((size_t)EE*NHEADSC*2);   // 25.6 MB (bf16; fp32 p_out aliased later)
  float* scale     = (float*)alloc((size_t)NN*NHEADSC*4);   // 3.2 MB
  u16*   outA      = (u16*)  alloc((size_t)NN*NCLASSC*2);   // 8 MB
  float* s_out     = (float*)alloc((size_t)NN*4);
  float* t_out     = (float*)alloc((size_t)NN*4);
  float* scale_out = (float*)alloc((size_t)NN*4);
  int*   counts    = (int*)  alloc((size_t)NN*4);
  u16*   Wt        = (u16*)  alloc((size_t)FDIM*NFEATC*2);
  float* p_out     = (float*)p_all;                         // alias: p_all dead after phase 3

  // phase 1: feature transform + per-head s,t
  k_transposeW<<<(FDIM*NFEATC+255)/256, 256, 0, stream>>>(W, Wt);
  k_gemm1<<<NN/32, 256, 0, stream>>>(x, Wt, h0);
  k_st<<<(NN*NHEADSC+255)/256, 256, 0, stream>>>(h0, a_src, a_dst, s, t_);

  // phase 2: CSR build
  k_zero<<<(NN+255)/256, 256, 0, stream>>>(counts, NN);
  k_count<<<(EE+255)/256, 256, 0, stream>>>(e_dst, counts);
  k_scan<<<1, 1024, 0, stream>>>(counts, row_start);
  k_zero<<<(NN+255)/256, 256, 0, stream>>>(counts, NN);
  k_scatter<<<(EE+255)/256, 256, 0, stream>>>(e_src, e_dst, row_start, counts, csr_src);

  // phase 3: single attention pass (all heads), then per-quarter hops
  k_att<<<(NN*NHEADSC+255)/256, 256, 0, stream>>>(s, t_, row_start, csr_src, p_all, scale);
  k_zero_f<<<(NN*NCLASSC+255)/256, 256, 0, stream>>>(out0, NN*NCLASSC);
  for (int q=0; q<NQ; q++){
    k_hop1q<<<NN/4, 256, 0, stream>>>(h0, p_all, scale, row_start, csr_src, featAq, q);
    k_hop2q<<<NN/4, 256, 0, stream>>>(featAq, h0, p_all, scale, row_start, csr_src, W_out, out0, q);
  }

  // phase 4: output layer (p precomputed fp32, aliased into p_all)
  k_st_out<<<(NN+255)/256, 256, 0, stream>>>(out0, a_src_o, a_dst_o, s_out, t_out);
  k_att_out<<<(NN+255)/256, 256, 0, stream>>>(s_out, t_out, row_start, csr_src, p_out, scale_out);
  k_hop1_out<<<NN, 64, 0, stream>>>(out0, p_out, scale_out, row_start, csr_src, outA);
  k_hop2_out_final<<<NN, 64, 0, stream>>>(outA, out0, p_out, scale_out, row_start, csr_src, out);
}

// Round 7
// 1419.402 us; speedup vs baseline: 1.7670x; 1.2179x over previous
//
#include <hip/hip_runtime.h>
#include <stdint.h>

#define NN      100000
#define EE      1600000
#define NFEATC  128
#define NHIDC   32
#define NHEADSC 8
#define NCLASSC 40
#define FDIM    256     // NHEADS*NHID
#define QF      64      // channels per quarter
#define NQ      4

typedef unsigned short u16;
typedef __attribute__((ext_vector_type(8))) short bf16x8;
typedef __attribute__((ext_vector_type(4))) float f32x4;

__device__ __forceinline__ float b2f(u16 u){ union{uint32_t i; float f;} v; v.i=((uint32_t)u)<<16; return v.f; }
__device__ __forceinline__ u16 f2b(float f){ union{float f; uint32_t i;} v; v.f=f; uint32_t x=v.i; return (u16)((x + 0x7FFFu + ((x>>16)&1u))>>16); }
__device__ __forceinline__ float lrelu(float e){ return e > 0.f ? e : 0.2f*e; }

// ---------------- W transpose+cast: Wt[c][k] = bf16(W[head][k][hid]) -------
__global__ __launch_bounds__(256) void k_transposeW(const float* __restrict__ W, u16* __restrict__ Wt){
  int i = blockIdx.x*256 + threadIdx.x;
  if (i >= FDIM*NFEATC) return;
  int c = i >> 7, k = i & 127;
  int head = c >> 5, hid = c & 31;
  Wt[c*NFEATC + k] = f2b(W[head*(NFEATC*NHIDC) + k*NHIDC + hid]);
}

// ---------------- GEMM1 via MFMA: h0 = x @ W  (bf16 out) -------------------
// wave = 16 nodes x 64 cols (4 col-tiles); block = 4 waves = 16 nodes x 256.
// A[m=lane&15][k=q*8+j], B[k=q*8+j][n=lane&15], D[row=q*4+r][col=lane&15].
__global__ __launch_bounds__(256) void k_gemm1_mfma(const float* __restrict__ x, const u16* __restrict__ Wt,
                                                    u16* __restrict__ h0){
  int w = threadIdx.x >> 6, lane = threadIdx.x & 63;
  int nt = blockIdx.x;
  int m = lane & 15, q = lane >> 4;
  int row = nt*16 + m;
  int c0 = w*64;
  const float* xrow = x + (size_t)row*NFEATC;
  f32x4 acc0 = {0.f,0.f,0.f,0.f}, acc1 = {0.f,0.f,0.f,0.f};
  f32x4 acc2 = {0.f,0.f,0.f,0.f}, acc3 = {0.f,0.f,0.f,0.f};
  #pragma unroll
  for (int kk=0; kk<NFEATC; kk+=32){
    int ko = kk + q*8;
    float4 xa = *(const float4*)(xrow + ko);
    float4 xb = *(const float4*)(xrow + ko + 4);
    bf16x8 a;
    a[0]=(short)f2b(xa.x); a[1]=(short)f2b(xa.y); a[2]=(short)f2b(xa.z); a[3]=(short)f2b(xa.w);
    a[4]=(short)f2b(xb.x); a[5]=(short)f2b(xb.y); a[6]=(short)f2b(xb.z); a[7]=(short)f2b(xb.w);
    bf16x8 b0 = *(const bf16x8*)(Wt + (size_t)(c0 +  0 + m)*NFEATC + ko);
    bf16x8 b1 = *(const bf16x8*)(Wt + (size_t)(c0 + 16 + m)*NFEATC + ko);
    bf16x8 b2 = *(const bf16x8*)(Wt + (size_t)(c0 + 32 + m)*NFEATC + ko);
    bf16x8 b3 = *(const bf16x8*)(Wt + (size_t)(c0 + 48 + m)*NFEATC + ko);
    acc0 = __builtin_amdgcn_mfma_f32_16x16x32_bf16(a, b0, acc0, 0,0,0);
    acc1 = __builtin_amdgcn_mfma_f32_16x16x32_bf16(a, b1, acc1, 0,0,0);
    acc2 = __builtin_amdgcn_mfma_f32_16x16x32_bf16(a, b2, acc2, 0,0,0);
    acc3 = __builtin_amdgcn_mfma_f32_16x16x32_bf16(a, b3, acc3, 0,0,0);
  }
  #pragma unroll
  for (int r=0; r<4; r++){
    size_t base = (size_t)(nt*16 + q*4 + r)*FDIM + c0 + m;
    h0[base +  0] = f2b(acc0[r]);
    h0[base + 16] = f2b(acc1[r]);
    h0[base + 32] = f2b(acc2[r]);
    h0[base + 48] = f2b(acc3[r]);
  }
}

// ---------------- s,t per (node,head), bf16 --------------------------------
__global__ __launch_bounds__(256) void k_st(const u16* __restrict__ h0, const float* __restrict__ a_src,
                                            const float* __restrict__ a_dst, u16* __restrict__ s,
                                            u16* __restrict__ t_){
  int i = blockIdx.x*256 + threadIdx.x;
  if (i >= NN*NHEADSC) return;
  int n = i>>3, head = i&7;
  const u16* hp = h0 + (size_t)n*FDIM + head*NHIDC;
  const float* ap = a_src + head*NHIDC;
  const float* bp = a_dst + head*NHIDC;
  float ss=0.f, tt=0.f;
  #pragma unroll
  for (int j=0;j<NHIDC;j++){
    float h = b2f(hp[j]);
    ss = fmaf(h, ap[j], ss); tt = fmaf(h, bp[j], tt);
  }
  s[i]=f2b(ss); t_[i]=f2b(tt);
}

// ---------------- CSR build ------------------------------------------------
__global__ __launch_bounds__(256) void k_zero(int* __restrict__ p, int n){
  int i = blockIdx.x*256 + threadIdx.x;
  if (i < n) p[i] = 0;
}
__global__ __launch_bounds__(256) void k_zero_f(float* __restrict__ p, int n){
  int i = blockIdx.x*256 + threadIdx.x;
  if (i < n) p[i] = 0.f;
}
__global__ __launch_bounds__(256) void k_count(const int* __restrict__ dst, int* __restrict__ counts){
  int e = blockIdx.x*256 + threadIdx.x;
  if (e < EE) atomicAdd(&counts[dst[e]], 1);
}
__global__ __launch_bounds__(1024) void k_scan(const int* __restrict__ counts, int* __restrict__ row_start){
  __shared__ int lds[1024];
  int t = threadIdx.x;
  const int CH = 98;
  int beg = t*CH;
  int sum = 0;
  for (int i=0;i<CH;i++){ int idx=beg+i; if (idx<NN) sum += counts[idx]; }
  lds[t]=sum; __syncthreads();
  for (int off=1; off<1024; off<<=1){
    int v = (t>=off) ? lds[t-off] : 0;
    __syncthreads();
    lds[t] += v;
    __syncthreads();
  }
  int run = lds[t] - sum;
  for (int i=0;i<CH;i++){ int idx=beg+i; if (idx<NN){ row_start[idx]=run; run += counts[idx]; } }
  if (t==0) row_start[NN] = EE;
}
__global__ __launch_bounds__(256) void k_scatter(const int* __restrict__ src, const int* __restrict__ dst,
                                                 const int* __restrict__ row_start, int* __restrict__ fill,
                                                 int* __restrict__ csr_src){
  int e = blockIdx.x*256 + threadIdx.x;
  if (e >= EE) return;
  int d = dst[e];
  int pos = row_start[d] + atomicAdd(&fill[d], 1);
  csr_src[pos] = src[e];
}

// ---------------- attention, all 8 heads: p_all (bf16) + inv-denominator ---
__global__ __launch_bounds__(256) void k_att(const u16* __restrict__ s, const u16* __restrict__ t_,
                                             const int* __restrict__ row_start, const int* __restrict__ csr_src,
                                             u16* __restrict__ p_all, float* __restrict__ scale){
  int i = blockIdx.x*256 + threadIdx.x;
  if (i >= NN*NHEADSC) return;
  int n = i>>3, head = i&7;
  int beg = row_start[n], end = row_start[n+1];
  float tn = b2f(t_[i]);
  float d0=0.f,d1=0.f,d2=0.f,d3=0.f;
  int pos = beg;
  for (; pos+4<=end; pos+=4){
    int u0=csr_src[pos], u1=csr_src[pos+1], u2=csr_src[pos+2], u3=csr_src[pos+3];
    float e0=lrelu(b2f(s[u0*NHEADSC+head])+tn);
    float e1=lrelu(b2f(s[u1*NHEADSC+head])+tn);
    float e2=lrelu(b2f(s[u2*NHEADSC+head])+tn);
    float e3=lrelu(b2f(s[u3*NHEADSC+head])+tn);
    u16 p0=f2b(__expf(e0)), p1=f2b(__expf(e1)), p2=f2b(__expf(e2)), p3=f2b(__expf(e3));
    p_all[(size_t)(pos+0)*NHEADSC+head]=p0;
    p_all[(size_t)(pos+1)*NHEADSC+head]=p1;
    p_all[(size_t)(pos+2)*NHEADSC+head]=p2;
    p_all[(size_t)(pos+3)*NHEADSC+head]=p3;
    d0+=b2f(p0); d1+=b2f(p1); d2+=b2f(p2); d3+=b2f(p3);
  }
  for (; pos<end; pos++){
    int u = csr_src[pos];
    float e = lrelu(b2f(s[u*NHEADSC+head])+tn);
    u16 pb = f2b(__expf(e));
    p_all[(size_t)pos*NHEADSC+head]=pb;
    d0 += b2f(pb);
  }
  scale[i] = 1.0f/(((d0+d1)+(d2+d3)) + 1e-16f);
}

// ---------------- hop1 (quarter): wave per node, 64 channels, unroll x4 ----
__global__ __launch_bounds__(256) void k_hop1q(const u16* __restrict__ h0, const u16* __restrict__ p_all,
                                               const float* __restrict__ scale, const int* __restrict__ row_start,
                                               const int* __restrict__ csr_src, u16* __restrict__ featAq, int q){
  int wv = threadIdx.x >> 6, l = threadIdx.x & 63;
  int n = blockIdx.x*4 + wv;
  int head = q*2 + (l>>5);
  int cg = q*QF + l;
  float sc_ = scale[n*NHEADSC + head];
  int beg = row_start[n], end = row_start[n+1];
  float a0=0.f,a1=0.f,a2=0.f,a3=0.f;
  int pos = beg;
  for (; pos+4<=end; pos+=4){
    int u0=csr_src[pos], u1=csr_src[pos+1], u2=csr_src[pos+2], u3=csr_src[pos+3];
    float p0=b2f(p_all[(size_t)(pos+0)*NHEADSC+head]);
    float p1=b2f(p_all[(size_t)(pos+1)*NHEADSC+head]);
    float p2=b2f(p_all[(size_t)(pos+2)*NHEADSC+head]);
    float p3=b2f(p_all[(size_t)(pos+3)*NHEADSC+head]);
    float g0=b2f(h0[(size_t)u0*FDIM+cg]);
    float g1=b2f(h0[(size_t)u1*FDIM+cg]);
    float g2=b2f(h0[(size_t)u2*FDIM+cg]);
    float g3=b2f(h0[(size_t)u3*FDIM+cg]);
    a0=fmaf(p0,g0,a0); a1=fmaf(p1,g1,a1); a2=fmaf(p2,g2,a2); a3=fmaf(p3,g3,a3);
  }
  for (; pos<end; pos++){
    int u=csr_src[pos];
    a0=fmaf(b2f(p_all[(size_t)pos*NHEADSC+head]), b2f(h0[(size_t)u*FDIM+cg]), a0);
  }
  float acc=(a0+a1)+(a2+a3);
  float res = 0.9f*sc_*acc + 0.1f*b2f(h0[(size_t)n*FDIM + cg]);
  featAq[(size_t)n*QF + l] = f2b(res);
}

// ---------------- hop2 (quarter) + elu + GEMM2 partial, unroll x4 ----------
__global__ __launch_bounds__(256) void k_hop2q(const u16* __restrict__ featAq, const u16* __restrict__ h0,
                                               const u16* __restrict__ p_all, const float* __restrict__ scale,
                                               const int* __restrict__ row_start, const int* __restrict__ csr_src,
                                               const float* __restrict__ W_out, float* __restrict__ out0, int q){
  __shared__ float hs[4][QF];
  int wv = threadIdx.x >> 6, l = threadIdx.x & 63;
  int n = blockIdx.x*4 + wv;
  int head = q*2 + (l>>5);
  int cg = q*QF + l;
  float sc_ = scale[n*NHEADSC + head];
  int beg = row_start[n], end = row_start[n+1];
  float a0=0.f,a1=0.f,a2=0.f,a3=0.f;
  int pos = beg;
  for (; pos+4<=end; pos+=4){
    int u0=csr_src[pos], u1=csr_src[pos+1], u2=csr_src[pos+2], u3=csr_src[pos+3];
    float p0=b2f(p_all[(size_t)(pos+0)*NHEADSC+head]);
    float p1=b2f(p_all[(size_t)(pos+1)*NHEADSC+head]);
    float p2=b2f(p_all[(size_t)(pos+2)*NHEADSC+head]);
    float p3=b2f(p_all[(size_t)(pos+3)*NHEADSC+head]);
    float g0=b2f(featAq[(size_t)u0*QF+l]);
    float g1=b2f(featAq[(size_t)u1*QF+l]);
    float g2=b2f(featAq[(size_t)u2*QF+l]);
    float g3=b2f(featAq[(size_t)u3*QF+l]);
    a0=fmaf(p0,g0,a0); a1=fmaf(p1,g1,a1); a2=fmaf(p2,g2,a2); a3=fmaf(p3,g3,a3);
  }
  for (; pos<end; pos++){
    int u=csr_src[pos];
    a0=fmaf(b2f(p_all[(size_t)pos*NHEADSC+head]), b2f(featAq[(size_t)u*QF+l]), a0);
  }
  float acc=(a0+a1)+(a2+a3);
  float res = 0.9f*sc_*acc + 0.1f*b2f(h0[(size_t)n*FDIM + cg]);
  hs[wv][l] = res > 0.f ? res : (__expf(res)-1.0f);   // elu per head
  __syncthreads();
  if (l < NCLASSC){
    float o = 0.f;
    #pragma unroll 8
    for (int k=0;k<QF;k++) o = fmaf(hs[wv][k], W_out[(q*QF+k)*NCLASSC + l], o);
    out0[(size_t)n*NCLASSC + l] += o;    // unique (n,l); quarters stream-serialized
  }
}

// ---------------- output-layer s,t -----------------------------------------
__global__ __launch_bounds__(256) void k_st_out(const float* __restrict__ out0, const float* __restrict__ a_s,
                                                const float* __restrict__ a_d, float* __restrict__ s,
                                                float* __restrict__ t_){
  int n = blockIdx.x*256 + threadIdx.x;
  if (n >= NN) return;
  const float* r = out0 + (size_t)n*NCLASSC;
  float ss=0.f, tt=0.f;
  for (int c=0;c<NCLASSC;c++){ float v=r[c]; ss=fmaf(v,a_s[c],ss); tt=fmaf(v,a_d[c],tt); }
  s[n]=ss; t_[n]=tt;
}

// ---------------- output-layer attention: p (fp32), unroll x4 --------------
__global__ __launch_bounds__(256) void k_att_out(const float* __restrict__ s, const float* __restrict__ t_,
                                                 const int* __restrict__ row_start, const int* __restrict__ csr_src,
                                                 float* __restrict__ p_out, float* __restrict__ scale_out){
  int n = blockIdx.x*256 + threadIdx.x;
  if (n >= NN) return;
  int beg = row_start[n], end = row_start[n+1];
  float tn = t_[n];
  float d0=0.f,d1=0.f,d2=0.f,d3=0.f;
  int pos = beg;
  for (; pos+4<=end; pos+=4){
    int u0=csr_src[pos], u1=csr_src[pos+1], u2=csr_src[pos+2], u3=csr_src[pos+3];
    float p0=__expf(lrelu(s[u0]+tn));
    float p1=__expf(lrelu(s[u1]+tn));
    float p2=__expf(lrelu(s[u2]+tn));
    float p3=__expf(lrelu(s[u3]+tn));
    p_out[pos]=p0; p_out[pos+1]=p1; p_out[pos+2]=p2; p_out[pos+3]=p3;
    d0+=p0; d1+=p1; d2+=p2; d3+=p3;
  }
  for (; pos<end; pos++){
    float p = __expf(lrelu(s[csr_src[pos]]+tn));
    p_out[pos] = p;
    d0 += p;
  }
  scale_out[n] = 1.0f/(((d0+d1)+(d2+d3)) + 1e-16f);
}

// ---------------- output-layer hop 1, unroll x4 ----------------------------
__global__ __launch_bounds__(64) void k_hop1_out(const float* __restrict__ out0, const float* __restrict__ p_out,
                                                 const float* __restrict__ scale_out, const int* __restrict__ row_start,
                                                 const int* __restrict__ csr_src, u16* __restrict__ outA){
  int n = blockIdx.x, t = threadIdx.x;
  float sc_ = scale_out[n];
  int beg = row_start[n], end = row_start[n+1];
  int tc = (t < NCLASSC) ? t : 0;
  float a0=0.f,a1=0.f,a2=0.f,a3=0.f;
  int pos = beg;
  for (; pos+4<=end; pos+=4){
    int u0=csr_src[pos], u1=csr_src[pos+1], u2=csr_src[pos+2], u3=csr_src[pos+3];
    float p0=p_out[pos], p1=p_out[pos+1], p2=p_out[pos+2], p3=p_out[pos+3];
    float f0=out0[(size_t)u0*NCLASSC+tc];
    float f1=out0[(size_t)u1*NCLASSC+tc];
    float f2=out0[(size_t)u2*NCLASSC+tc];
    float f3=out0[(size_t)u3*NCLASSC+tc];
    a0=fmaf(p0,f0,a0); a1=fmaf(p1,f1,a1); a2=fmaf(p2,f2,a2); a3=fmaf(p3,f3,a3);
  }
  for (; pos<end; pos++){
    a0=fmaf(p_out[pos], out0[(size_t)csr_src[pos]*NCLASSC+tc], a0);
  }
  if (t < NCLASSC){
    float res = 0.9f*sc_*((a0+a1)+(a2+a3)) + 0.1f*out0[(size_t)n*NCLASSC + t];
    outA[(size_t)n*NCLASSC + t] = f2b(res);
  }
}

// ---------------- output-layer hop 2 + elu + log_softmax, unroll x4 --------
__global__ __launch_bounds__(64) void k_hop2_out_final(const u16* __restrict__ outA, const float* __restrict__ out0,
                                                       const float* __restrict__ p_out, const float* __restrict__ scale_out,
                                                       const int* __restrict__ row_start, const int* __restrict__ csr_src,
                                                       float* __restrict__ out){
  int n = blockIdx.x, t = threadIdx.x;
  float sc_ = scale_out[n];
  int beg = row_start[n], end = row_start[n+1];
  int tc = (t < NCLASSC) ? t : 0;
  float a0=0.f,a1=0.f,a2=0.f,a3=0.f;
  int pos = beg;
  for (; pos+4<=end; pos+=4){
    int u0=csr_src[pos], u1=csr_src[pos+1], u2=csr_src[pos+2], u3=csr_src[pos+3];
    float p0=p_out[pos], p1=p_out[pos+1], p2=p_out[pos+2], p3=p_out[pos+3];
    float f0=b2f(outA[(size_t)u0*NCLASSC+tc]);
    float f1=b2f(outA[(size_t)u1*NCLASSC+tc]);
    float f2=b2f(outA[(size_t)u2*NCLASSC+tc]);
    float f3=b2f(outA[(size_t)u3*NCLASSC+tc]);
    a0=fmaf(p0,f0,a0); a1=fmaf(p1,f1,a1); a2=fmaf(p2,f2,a2); a3=fmaf(p3,f3,a3);
  }
  for (; pos<end; pos++){
    a0=fmaf(p_out[pos], b2f(outA[(size_t)csr_src[pos]*NCLASSC+tc]), a0);
  }
  float v = -1e30f;
  if (t < NCLASSC){
    float res = 0.9f*sc_*((a0+a1)+(a2+a3)) + 0.1f*out0[(size_t)n*NCLASSC + t];
    v = res > 0.f ? res : (__expf(res)-1.0f);
  }
  float m = v;
  #pragma unroll
  for (int off=32; off; off>>=1) m = fmaxf(m, __shfl_xor(m, off));
  float ex = (t < NCLASSC) ? __expf(v - m) : 0.f;
  float ssum = ex;
  #pragma unroll
  for (int off=32; off; off>>=1) ssum += __shfl_xor(ssum, off);
  if (t < NCLASSC) out[(size_t)n*NCLASSC + t] = v - m - __logf(ssum);
}

extern "C" void kernel_launch(void* const* d_in, const int* in_sizes, int n_in,
                              void* d_out, int out_size, void* d_ws, size_t ws_size,
                              hipStream_t stream){
  const float* x        = (const float*)d_in[0];
  const int*   ei       = (const int*)d_in[1];
  const float* W        = (const float*)d_in[2];
  const float* a_src    = (const float*)d_in[3];
  const float* a_dst    = (const float*)d_in[4];
  const float* W_out    = (const float*)d_in[5];
  const float* a_src_o  = (const float*)d_in[6];
  const float* a_dst_o  = (const float*)d_in[7];
  float* out            = (float*)d_out;
  const int* e_src = ei;
  const int* e_dst = ei + EE;

  // ---- workspace: ~129 MB (<=157 MB proven safe) ----
  char* ws = (char*)d_ws;
  size_t off = 0;
  auto alloc = [&](size_t bytes)->char*{ char* p = ws + off; off += (bytes + 255) & ~(size_t)255; return p; };

  u16*   h0        = (u16*)  alloc((size_t)NN*FDIM*2);      // 51.2 MB
  u16*   featAq    = (u16*)  alloc((size_t)NN*QF*2);        // 12.8 MB
  float* out0      = (float*)alloc((size_t)NN*NCLASSC*4);   // 16 MB
  int*   csr_src   = (int*)  alloc((size_t)EE*4);           // 6.4 MB
  int*   row_start = (int*)  alloc((size_t)(NN+1)*4);       // 0.4 MB
  u16*   s         = (u16*)  alloc((size_t)NN*NHEADSC*2);   // 1.6 MB
  u16*   t_        = (u16*)  alloc((size_t)NN*NHEADSC*2);   // 1.6 MB
  u16*   p_all     = (u16*)  alloc((size_t)EE*NHEADSC*2);   // 25.6 MB (bf16; fp32 p_out aliased later)
  float* scale     = (float*)alloc((size_t)NN*NHEADSC*4);   // 3.2 MB
  u16*   outA      = (u16*)  alloc((size_t)NN*NCLASSC*2);   // 8 MB
  float* s_out     = (float*)alloc((size_t)NN*4);
  float* t_out     = (float*)alloc((size_t)NN*4);
  float* scale_out = (float*)alloc((size_t)NN*4);
  int*   counts    = (int*)  alloc((size_t)NN*4);
  u16*   Wt        = (u16*)  alloc((size_t)FDIM*NFEATC*2);
  float* p_out     = (float*)p_all;                         // alias: p_all dead after phase 3

  // phase 1: feature transform (MFMA) + per-head s,t
  k_transposeW<<<(FDIM*NFEATC+255)/256, 256, 0, stream>>>(W, Wt);
  k_gemm1_mfma<<<NN/16, 256, 0, stream>>>(x, Wt, h0);
  k_st<<<(NN*NHEADSC+255)/256, 256, 0, stream>>>(h0, a_src, a_dst, s, t_);

  // phase 2: CSR build
  k_zero<<<(NN+255)/256, 256, 0, stream>>>(counts, NN);
  k_count<<<(EE+255)/256, 256, 0, stream>>>(e_dst, counts);
  k_scan<<<1, 1024, 0, stream>>>(counts, row_start);
  k_zero<<<(NN+255)/256, 256, 0, stream>>>(counts, NN);
  k_scatter<<<(EE+255)/256, 256, 0, stream>>>(e_src, e_dst, row_start, counts, csr_src);

  // phase 3: single attention pass (all heads), then per-quarter hops
  k_att<<<(NN*NHEADSC+255)/256, 256, 0, stream>>>(s, t_, row_start, csr_src, p_all, scale);
  k_zero_f<<<(NN*NCLASSC+255)/256, 256, 0, stream>>>(out0, NN*NCLASSC);
  for (int q=0; q<NQ; q++){
    k_hop1q<<<NN/4, 256, 0, stream>>>(h0, p_all, scale, row_start, csr_src, featAq, q);
    k_hop2q<<<NN/4, 256, 0, stream>>>(featAq, h0, p_all, scale, row_start, csr_src, W_out, out0, q);
  }

  // phase 4: output layer (p precomputed fp32, aliased into p_all)
  k_st_out<<<(NN+255)/256, 256, 0, stream>>>(out0, a_src_o, a_dst_o, s_out, t_out);
  k_att_out<<<(NN+255)/256, 256, 0, stream>>>(s_out, t_out, row_start, csr_src, p_out, scale_out);
  k_hop1_out<<<NN, 64, 0, stream>>>(out0, p_out, scale_out, row_start, csr_src, outA);
  k_hop2_out_final<<<NN, 64, 0, stream>>>(outA, out0, p_out, scale_out, row_start, csr_src, out);
}

// Round 8
// 1234.757 us; speedup vs baseline: 2.0312x; 1.1495x over previous
//
#include <hip/hip_runtime.h>
#include <stdint.h>

#define NN      100000
#define EE      1600000
#define NFEATC  128
#define NHIDC   32
#define NHEADSC 8
#define NCLASSC 40
#define FDIM    256     // NHEADS*NHID
#define QF      64      // channels per quarter
#define NQ      4
#define NBLK    ((NN+255)/256)   // 391

typedef unsigned short u16;
typedef __attribute__((ext_vector_type(8))) short bf16x8;
typedef __attribute__((ext_vector_type(4))) float f32x4;

__device__ __forceinline__ float b2f(u16 u){ union{uint32_t i; float f;} v; v.i=((uint32_t)u)<<16; return v.f; }
__device__ __forceinline__ u16 f2b(float f){ union{float f; uint32_t i;} v; v.f=f; uint32_t x=v.i; return (u16)((x + 0x7FFFu + ((x>>16)&1u))>>16); }
__device__ __forceinline__ float lrelu(float e){ return e > 0.f ? e : 0.2f*e; }

// ---------------- W transpose+cast: Wt[c][k] = bf16(W[head][k][hid]) -------
__global__ __launch_bounds__(256) void k_transposeW(const float* __restrict__ W, u16* __restrict__ Wt){
  int i = blockIdx.x*256 + threadIdx.x;
  if (i >= FDIM*NFEATC) return;
  int c = i >> 7, k = i & 127;
  int head = c >> 5, hid = c & 31;
  Wt[c*NFEATC + k] = f2b(W[head*(NFEATC*NHIDC) + k*NHIDC + hid]);
}

// ---------------- GEMM1 via MFMA: h0 = x @ W  (bf16 out) -------------------
__global__ __launch_bounds__(256) void k_gemm1_mfma(const float* __restrict__ x, const u16* __restrict__ Wt,
                                                    u16* __restrict__ h0){
  int w = threadIdx.x >> 6, lane = threadIdx.x & 63;
  int nt = blockIdx.x;
  int m = lane & 15, q = lane >> 4;
  int row = nt*16 + m;
  int c0 = w*64;
  const float* xrow = x + (size_t)row*NFEATC;
  f32x4 acc0 = {0.f,0.f,0.f,0.f}, acc1 = {0.f,0.f,0.f,0.f};
  f32x4 acc2 = {0.f,0.f,0.f,0.f}, acc3 = {0.f,0.f,0.f,0.f};
  #pragma unroll
  for (int kk=0; kk<NFEATC; kk+=32){
    int ko = kk + q*8;
    float4 xa = *(const float4*)(xrow + ko);
    float4 xb = *(const float4*)(xrow + ko + 4);
    bf16x8 a;
    a[0]=(short)f2b(xa.x); a[1]=(short)f2b(xa.y); a[2]=(short)f2b(xa.z); a[3]=(short)f2b(xa.w);
    a[4]=(short)f2b(xb.x); a[5]=(short)f2b(xb.y); a[6]=(short)f2b(xb.z); a[7]=(short)f2b(xb.w);
    bf16x8 b0 = *(const bf16x8*)(Wt + (size_t)(c0 +  0 + m)*NFEATC + ko);
    bf16x8 b1 = *(const bf16x8*)(Wt + (size_t)(c0 + 16 + m)*NFEATC + ko);
    bf16x8 b2 = *(const bf16x8*)(Wt + (size_t)(c0 + 32 + m)*NFEATC + ko);
    bf16x8 b3 = *(const bf16x8*)(Wt + (size_t)(c0 + 48 + m)*NFEATC + ko);
    acc0 = __builtin_amdgcn_mfma_f32_16x16x32_bf16(a, b0, acc0, 0,0,0);
    acc1 = __builtin_amdgcn_mfma_f32_16x16x32_bf16(a, b1, acc1, 0,0,0);
    acc2 = __builtin_amdgcn_mfma_f32_16x16x32_bf16(a, b2, acc2, 0,0,0);
    acc3 = __builtin_amdgcn_mfma_f32_16x16x32_bf16(a, b3, acc3, 0,0,0);
  }
  #pragma unroll
  for (int r=0; r<4; r++){
    size_t base = (size_t)(nt*16 + q*4 + r)*FDIM + c0 + m;
    h0[base +  0] = f2b(acc0[r]);
    h0[base + 16] = f2b(acc1[r]);
    h0[base + 32] = f2b(acc2[r]);
    h0[base + 48] = f2b(acc3[r]);
  }
}

// ---------------- s,t per (node,head), bf16 --------------------------------
__global__ __launch_bounds__(256) void k_st(const u16* __restrict__ h0, const float* __restrict__ a_src,
                                            const float* __restrict__ a_dst, u16* __restrict__ s,
                                            u16* __restrict__ t_){
  int i = blockIdx.x*256 + threadIdx.x;
  if (i >= NN*NHEADSC) return;
  int n = i>>3, head = i&7;
  const u16* hp = h0 + (size_t)n*FDIM + head*NHIDC;
  const float* ap = a_src + head*NHIDC;
  const float* bp = a_dst + head*NHIDC;
  float ss=0.f, tt=0.f;
  #pragma unroll
  for (int j=0;j<NHIDC;j++){
    float h = b2f(hp[j]);
    ss = fmaf(h, ap[j], ss); tt = fmaf(h, bp[j], tt);
  }
  s[i]=f2b(ss); t_[i]=f2b(tt);
}

// ---------------- CSR build ------------------------------------------------
__global__ __launch_bounds__(256) void k_zero(int* __restrict__ p, int n){
  int i = blockIdx.x*256 + threadIdx.x;
  if (i < n) p[i] = 0;
}
__global__ __launch_bounds__(256) void k_zero_f(float* __restrict__ p, int n){
  int i = blockIdx.x*256 + threadIdx.x;
  if (i < n) p[i] = 0.f;
}
__global__ __launch_bounds__(256) void k_count(const int* __restrict__ dst, int* __restrict__ counts){
  int e = blockIdx.x*256 + threadIdx.x;
  if (e < EE) atomicAdd(&counts[dst[e]], 1);
}
// hierarchical scan: blocksum -> scan of 391 sums -> intra-block scan + offset
__global__ __launch_bounds__(256) void k_blocksum(const int* __restrict__ counts, int* __restrict__ bsum){
  __shared__ int wsum[4];
  int b = blockIdx.x, t = threadIdx.x;
  int i = b*256 + t;
  int v = (i < NN) ? counts[i] : 0;
  #pragma unroll
  for (int off=32; off; off>>=1) v += __shfl_xor(v, off);
  if ((t & 63) == 0) wsum[t>>6] = v;
  __syncthreads();
  if (t == 0) bsum[b] = wsum[0]+wsum[1]+wsum[2]+wsum[3];
}
__global__ __launch_bounds__(512) void k_scan_bsum(const int* __restrict__ bsum, int* __restrict__ boff){
  __shared__ int lds[512];
  int t = threadIdx.x;
  int v = (t < NBLK) ? bsum[t] : 0;
  lds[t] = v; __syncthreads();
  for (int off=1; off<512; off<<=1){
    int u = (t>=off) ? lds[t-off] : 0;
    __syncthreads();
    lds[t] += u;
    __syncthreads();
  }
  if (t < NBLK) boff[t] = lds[t] - v;   // exclusive prefix
}
__global__ __launch_bounds__(256) void k_scan_final(const int* __restrict__ counts, const int* __restrict__ boff,
                                                    int* __restrict__ row_start){
  __shared__ int lds[256];
  int b = blockIdx.x, t = threadIdx.x;
  int i = b*256 + t;
  int v = (i < NN) ? counts[i] : 0;
  lds[t] = v; __syncthreads();
  for (int off=1; off<256; off<<=1){
    int u = (t>=off) ? lds[t-off] : 0;
    __syncthreads();
    lds[t] += u;
    __syncthreads();
  }
  if (i < NN) row_start[i] = boff[b] + lds[t] - v;
  if (b == 0 && t == 0) row_start[NN] = EE;
}
__global__ __launch_bounds__(256) void k_scatter(const int* __restrict__ src, const int* __restrict__ dst,
                                                 const int* __restrict__ row_start, int* __restrict__ fill,
                                                 int* __restrict__ csr_src){
  int e = blockIdx.x*256 + threadIdx.x;
  if (e >= EE) return;
  int d = dst[e];
  int pos = row_start[d] + atomicAdd(&fill[d], 1);
  csr_src[pos] = src[e];
}

// ---------------- attention, all 8 heads: p_all (bf16) + inv-denominator ---
__global__ __launch_bounds__(256) void k_att(const u16* __restrict__ s, const u16* __restrict__ t_,
                                             const int* __restrict__ row_start, const int* __restrict__ csr_src,
                                             u16* __restrict__ p_all, float* __restrict__ scale){
  int i = blockIdx.x*256 + threadIdx.x;
  if (i >= NN*NHEADSC) return;
  int n = i>>3, head = i&7;
  int beg = row_start[n], end = row_start[n+1];
  float tn = b2f(t_[i]);
  float d0=0.f,d1=0.f,d2=0.f,d3=0.f;
  int pos = beg;
  for (; pos+4<=end; pos+=4){
    int u0=csr_src[pos], u1=csr_src[pos+1], u2=csr_src[pos+2], u3=csr_src[pos+3];
    float e0=lrelu(b2f(s[u0*NHEADSC+head])+tn);
    float e1=lrelu(b2f(s[u1*NHEADSC+head])+tn);
    float e2=lrelu(b2f(s[u2*NHEADSC+head])+tn);
    float e3=lrelu(b2f(s[u3*NHEADSC+head])+tn);
    u16 p0=f2b(__expf(e0)), p1=f2b(__expf(e1)), p2=f2b(__expf(e2)), p3=f2b(__expf(e3));
    p_all[(size_t)(pos+0)*NHEADSC+head]=p0;
    p_all[(size_t)(pos+1)*NHEADSC+head]=p1;
    p_all[(size_t)(pos+2)*NHEADSC+head]=p2;
    p_all[(size_t)(pos+3)*NHEADSC+head]=p3;
    d0+=b2f(p0); d1+=b2f(p1); d2+=b2f(p2); d3+=b2f(p3);
  }
  for (; pos<end; pos++){
    int u = csr_src[pos];
    float e = lrelu(b2f(s[u*NHEADSC+head])+tn);
    u16 pb = f2b(__expf(e));
    p_all[(size_t)pos*NHEADSC+head]=pb;
    d0 += b2f(pb);
  }
  scale[i] = 1.0f/(((d0+d1)+(d2+d3)) + 1e-16f);
}

// ---------------- hop1 (quarter): wave per node, 64 channels, unroll x4 ----
__global__ __launch_bounds__(256) void k_hop1q(const u16* __restrict__ h0, const u16* __restrict__ p_all,
                                               const float* __restrict__ scale, const int* __restrict__ row_start,
                                               const int* __restrict__ csr_src, u16* __restrict__ featAq, int q){
  int wv = threadIdx.x >> 6, l = threadIdx.x & 63;
  int n = blockIdx.x*4 + wv;
  int head = q*2 + (l>>5);
  int cg = q*QF + l;
  float sc_ = scale[n*NHEADSC + head];
  int beg = row_start[n], end = row_start[n+1];
  float a0=0.f,a1=0.f,a2=0.f,a3=0.f;
  int pos = beg;
  for (; pos+4<=end; pos+=4){
    int u0=csr_src[pos], u1=csr_src[pos+1], u2=csr_src[pos+2], u3=csr_src[pos+3];
    float p0=b2f(p_all[(size_t)(pos+0)*NHEADSC+head]);
    float p1=b2f(p_all[(size_t)(pos+1)*NHEADSC+head]);
    float p2=b2f(p_all[(size_t)(pos+2)*NHEADSC+head]);
    float p3=b2f(p_all[(size_t)(pos+3)*NHEADSC+head]);
    float g0=b2f(h0[(size_t)u0*FDIM+cg]);
    float g1=b2f(h0[(size_t)u1*FDIM+cg]);
    float g2=b2f(h0[(size_t)u2*FDIM+cg]);
    float g3=b2f(h0[(size_t)u3*FDIM+cg]);
    a0=fmaf(p0,g0,a0); a1=fmaf(p1,g1,a1); a2=fmaf(p2,g2,a2); a3=fmaf(p3,g3,a3);
  }
  for (; pos<end; pos++){
    int u=csr_src[pos];
    a0=fmaf(b2f(p_all[(size_t)pos*NHEADSC+head]), b2f(h0[(size_t)u*FDIM+cg]), a0);
  }
  float acc=(a0+a1)+(a2+a3);
  float res = 0.9f*sc_*acc + 0.1f*b2f(h0[(size_t)n*FDIM + cg]);
  featAq[(size_t)n*QF + l] = f2b(res);
}

// ---------------- hop2 (quarter) + elu + GEMM2 partial, unroll x4 ----------
__global__ __launch_bounds__(256) void k_hop2q(const u16* __restrict__ featAq, const u16* __restrict__ h0,
                                               const u16* __restrict__ p_all, const float* __restrict__ scale,
                                               const int* __restrict__ row_start, const int* __restrict__ csr_src,
                                               const float* __restrict__ W_out, float* __restrict__ out0, int q){
  __shared__ float hs[4][QF];
  int wv = threadIdx.x >> 6, l = threadIdx.x & 63;
  int n = blockIdx.x*4 + wv;
  int head = q*2 + (l>>5);
  int cg = q*QF + l;
  float sc_ = scale[n*NHEADSC + head];
  int beg = row_start[n], end = row_start[n+1];
  float a0=0.f,a1=0.f,a2=0.f,a3=0.f;
  int pos = beg;
  for (; pos+4<=end; pos+=4){
    int u0=csr_src[pos], u1=csr_src[pos+1], u2=csr_src[pos+2], u3=csr_src[pos+3];
    float p0=b2f(p_all[(size_t)(pos+0)*NHEADSC+head]);
    float p1=b2f(p_all[(size_t)(pos+1)*NHEADSC+head]);
    float p2=b2f(p_all[(size_t)(pos+2)*NHEADSC+head]);
    float p3=b2f(p_all[(size_t)(pos+3)*NHEADSC+head]);
    float g0=b2f(featAq[(size_t)u0*QF+l]);
    float g1=b2f(featAq[(size_t)u1*QF+l]);
    float g2=b2f(featAq[(size_t)u2*QF+l]);
    float g3=b2f(featAq[(size_t)u3*QF+l]);
    a0=fmaf(p0,g0,a0); a1=fmaf(p1,g1,a1); a2=fmaf(p2,g2,a2); a3=fmaf(p3,g3,a3);
  }
  for (; pos<end; pos++){
    int u=csr_src[pos];
    a0=fmaf(b2f(p_all[(size_t)pos*NHEADSC+head]), b2f(featAq[(size_t)u*QF+l]), a0);
  }
  float acc=(a0+a1)+(a2+a3);
  float res = 0.9f*sc_*acc + 0.1f*b2f(h0[(size_t)n*FDIM + cg]);
  hs[wv][l] = res > 0.f ? res : (__expf(res)-1.0f);   // elu per head
  __syncthreads();
  if (l < NCLASSC){
    float o = 0.f;
    #pragma unroll 8
    for (int k=0;k<QF;k++) o = fmaf(hs[wv][k], W_out[(q*QF+k)*NCLASSC + l], o);
    out0[(size_t)n*NCLASSC + l] += o;    // unique (n,l); quarters stream-serialized
  }
}

// ---------------- output-layer s,t -----------------------------------------
__global__ __launch_bounds__(256) void k_st_out(const float* __restrict__ out0, const float* __restrict__ a_s,
                                                const float* __restrict__ a_d, float* __restrict__ s,
                                                float* __restrict__ t_){
  int n = blockIdx.x*256 + threadIdx.x;
  if (n >= NN) return;
  const float* r = out0 + (size_t)n*NCLASSC;
  float ss=0.f, tt=0.f;
  for (int c=0;c<NCLASSC;c++){ float v=r[c]; ss=fmaf(v,a_s[c],ss); tt=fmaf(v,a_d[c],tt); }
  s[n]=ss; t_[n]=tt;
}

// ---------------- output-layer attention: p (fp32), unroll x4 --------------
__global__ __launch_bounds__(256) void k_att_out(const float* __restrict__ s, const float* __restrict__ t_,
                                                 const int* __restrict__ row_start, const int* __restrict__ csr_src,
                                                 float* __restrict__ p_out, float* __restrict__ scale_out){
  int n = blockIdx.x*256 + threadIdx.x;
  if (n >= NN) return;
  int beg = row_start[n], end = row_start[n+1];
  float tn = t_[n];
  float d0=0.f,d1=0.f,d2=0.f,d3=0.f;
  int pos = beg;
  for (; pos+4<=end; pos+=4){
    int u0=csr_src[pos], u1=csr_src[pos+1], u2=csr_src[pos+2], u3=csr_src[pos+3];
    float p0=__expf(lrelu(s[u0]+tn));
    float p1=__expf(lrelu(s[u1]+tn));
    float p2=__expf(lrelu(s[u2]+tn));
    float p3=__expf(lrelu(s[u3]+tn));
    p_out[pos]=p0; p_out[pos+1]=p1; p_out[pos+2]=p2; p_out[pos+3]=p3;
    d0+=p0; d1+=p1; d2+=p2; d3+=p3;
  }
  for (; pos<end; pos++){
    float p = __expf(lrelu(s[csr_src[pos]]+tn));
    p_out[pos] = p;
    d0 += p;
  }
  scale_out[n] = 1.0f/(((d0+d1)+(d2+d3)) + 1e-16f);
}

// ---------------- output-layer hop 1, unroll x4 ----------------------------
__global__ __launch_bounds__(64) void k_hop1_out(const float* __restrict__ out0, const float* __restrict__ p_out,
                                                 const float* __restrict__ scale_out, const int* __restrict__ row_start,
                                                 const int* __restrict__ csr_src, u16* __restrict__ outA){
  int n = blockIdx.x, t = threadIdx.x;
  float sc_ = scale_out[n];
  int beg = row_start[n], end = row_start[n+1];
  int tc = (t < NCLASSC) ? t : 0;
  float a0=0.f,a1=0.f,a2=0.f,a3=0.f;
  int pos = beg;
  for (; pos+4<=end; pos+=4){
    int u0=csr_src[pos], u1=csr_src[pos+1], u2=csr_src[pos+2], u3=csr_src[pos+3];
    float p0=p_out[pos], p1=p_out[pos+1], p2=p_out[pos+2], p3=p_out[pos+3];
    float f0=out0[(size_t)u0*NCLASSC+tc];
    float f1=out0[(size_t)u1*NCLASSC+tc];
    float f2=out0[(size_t)u2*NCLASSC+tc];
    float f3=out0[(size_t)u3*NCLASSC+tc];
    a0=fmaf(p0,f0,a0); a1=fmaf(p1,f1,a1); a2=fmaf(p2,f2,a2); a3=fmaf(p3,f3,a3);
  }
  for (; pos<end; pos++){
    a0=fmaf(p_out[pos], out0[(size_t)csr_src[pos]*NCLASSC+tc], a0);
  }
  if (t < NCLASSC){
    float res = 0.9f*sc_*((a0+a1)+(a2+a3)) + 0.1f*out0[(size_t)n*NCLASSC + t];
    outA[(size_t)n*NCLASSC + t] = f2b(res);
  }
}

// ---------------- output-layer hop 2 + elu + log_softmax, unroll x4 --------
__global__ __launch_bounds__(64) void k_hop2_out_final(const u16* __restrict__ outA, const float* __restrict__ out0,
                                                       const float* __restrict__ p_out, const float* __restrict__ scale_out,
                                                       const int* __restrict__ row_start, const int* __restrict__ csr_src,
                                                       float* __restrict__ out){
  int n = blockIdx.x, t = threadIdx.x;
  float sc_ = scale_out[n];
  int beg = row_start[n], end = row_start[n+1];
  int tc = (t < NCLASSC) ? t : 0;
  float a0=0.f,a1=0.f,a2=0.f,a3=0.f;
  int pos = beg;
  for (; pos+4<=end; pos+=4){
    int u0=csr_src[pos], u1=csr_src[pos+1], u2=csr_src[pos+2], u3=csr_src[pos+3];
    float p0=p_out[pos], p1=p_out[pos+1], p2=p_out[pos+2], p3=p_out[pos+3];
    float f0=b2f(outA[(size_t)u0*NCLASSC+tc]);
    float f1=b2f(outA[(size_t)u1*NCLASSC+tc]);
    float f2=b2f(outA[(size_t)u2*NCLASSC+tc]);
    float f3=b2f(outA[(size_t)u3*NCLASSC+tc]);
    a0=fmaf(p0,f0,a0); a1=fmaf(p1,f1,a1); a2=fmaf(p2,f2,a2); a3=fmaf(p3,f3,a3);
  }
  for (; pos<end; pos++){
    a0=fmaf(p_out[pos], b2f(outA[(size_t)csr_src[pos]*NCLASSC+tc]), a0);
  }
  float v = -1e30f;
  if (t < NCLASSC){
    float res = 0.9f*sc_*((a0+a1)+(a2+a3)) + 0.1f*out0[(size_t)n*NCLASSC + t];
    v = res > 0.f ? res : (__expf(res)-1.0f);
  }
  float m = v;
  #pragma unroll
  for (int off=32; off; off>>=1) m = fmaxf(m, __shfl_xor(m, off));
  float ex = (t < NCLASSC) ? __expf(v - m) : 0.f;
  float ssum = ex;
  #pragma unroll
  for (int off=32; off; off>>=1) ssum += __shfl_xor(ssum, off);
  if (t < NCLASSC) out[(size_t)n*NCLASSC + t] = v - m - __logf(ssum);
}

extern "C" void kernel_launch(void* const* d_in, const int* in_sizes, int n_in,
                              void* d_out, int out_size, void* d_ws, size_t ws_size,
                              hipStream_t stream){
  const float* x        = (const float*)d_in[0];
  const int*   ei       = (const int*)d_in[1];
  const float* W        = (const float*)d_in[2];
  const float* a_src    = (const float*)d_in[3];
  const float* a_dst    = (const float*)d_in[4];
  const float* W_out    = (const float*)d_in[5];
  const float* a_src_o  = (const float*)d_in[6];
  const float* a_dst_o  = (const float*)d_in[7];
  float* out            = (float*)d_out;
  const int* e_src = ei;
  const int* e_dst = ei + EE;

  // ---- workspace: ~129 MB (<=157 MB proven safe) ----
  char* ws = (char*)d_ws;
  size_t off = 0;
  auto alloc = [&](size_t bytes)->char*{ char* p = ws + off; off += (bytes + 255) & ~(size_t)255; return p; };

  u16*   h0        = (u16*)  alloc((size_t)NN*FDIM*2);      // 51.2 MB
  u16*   featAq    = (u16*)  alloc((size_t)NN*QF*2);        // 12.8 MB
  float* out0      = (float*)alloc((size_t)NN*NCLASSC*4);   // 16 MB
  int*   csr_src   = (int*)  alloc((size_t)EE*4);           // 6.4 MB
  int*   row_start = (int*)  alloc((size_t)(NN+1)*4);       // 0.4 MB
  u16*   s         = (u16*)  alloc((size_t)NN*NHEADSC*2);   // 1.6 MB
  u16*   t_        = (u16*)  alloc((size_t)NN*NHEADSC*2);   // 1.6 MB
  u16*   p_all     = (u16*)  alloc((size_t)EE*NHEADSC*2);   // 25.6 MB (bf16; fp32 p_out aliased later)
  float* scale     = (float*)alloc((size_t)NN*NHEADSC*4);   // 3.2 MB
  u16*   outA      = (u16*)  alloc((size_t)NN*NCLASSC*2);   // 8 MB
  float* s_out     = (float*)alloc((size_t)NN*4);
  float* t_out     = (float*)alloc((size_t)NN*4);
  float* scale_out = (float*)alloc((size_t)NN*4);
  int*   counts    = (int*)  alloc((size_t)NN*4);
  int*   bsum      = (int*)  alloc((size_t)NBLK*4);
  int*   boff      = (int*)  alloc((size_t)NBLK*4);
  u16*   Wt        = (u16*)  alloc((size_t)FDIM*NFEATC*2);
  float* p_out     = (float*)p_all;                         // alias: p_all dead after phase 3

  // phase 1: feature transform (MFMA) + per-head s,t
  k_transposeW<<<(FDIM*NFEATC+255)/256, 256, 0, stream>>>(W, Wt);
  k_gemm1_mfma<<<NN/16, 256, 0, stream>>>(x, Wt, h0);
  k_st<<<(NN*NHEADSC+255)/256, 256, 0, stream>>>(h0, a_src, a_dst, s, t_);

  // phase 2: CSR build (hierarchical scan)
  k_zero<<<(NN+255)/256, 256, 0, stream>>>(counts, NN);
  k_count<<<(EE+255)/256, 256, 0, stream>>>(e_dst, counts);
  k_blocksum<<<NBLK, 256, 0, stream>>>(counts, bsum);
  k_scan_bsum<<<1, 512, 0, stream>>>(bsum, boff);
  k_scan_final<<<NBLK, 256, 0, stream>>>(counts, boff, row_start);
  k_zero<<<(NN+255)/256, 256, 0, stream>>>(counts, NN);
  k_scatter<<<(EE+255)/256, 256, 0, stream>>>(e_src, e_dst, row_start, counts, csr_src);

  // phase 3: single attention pass (all heads), then per-quarter hops
  k_att<<<(NN*NHEADSC+255)/256, 256, 0, stream>>>(s, t_, row_start, csr_src, p_all, scale);
  k_zero_f<<<(NN*NCLASSC+255)/256, 256, 0, stream>>>(out0, NN*NCLASSC);
  for (int q=0; q<NQ; q++){
    k_hop1q<<<NN/4, 256, 0, stream>>>(h0, p_all, scale, row_start, csr_src, featAq, q);
    k_hop2q<<<NN/4, 256, 0, stream>>>(featAq, h0, p_all, scale, row_start, csr_src, W_out, out0, q);
  }

  // phase 4: output layer (p precomputed fp32, aliased into p_all)
  k_st_out<<<(NN+255)/256, 256, 0, stream>>>(out0, a_src_o, a_dst_o, s_out, t_out);
  k_att_out<<<(NN+255)/256, 256, 0, stream>>>(s_out, t_out, row_start, csr_src, p_out, scale_out);
  k_hop1_out<<<NN, 64, 0, stream>>>(out0, p_out, scale_out, row_start, csr_src, outA);
  k_hop2_out_final<<<NN, 64, 0, stream>>>(outA, out0, p_out, scale_out, row_start, csr_src, out);
}

// Round 9
// 946.818 us; speedup vs baseline: 2.6489x; 1.3041x over previous
//
#include <hip/hip_runtime.h>
#include <stdint.h>

#define NN      100000
#define EE      1600000
#define NFEATC  128
#define NHIDC   32
#define NHEADSC 8
#define NCLASSC 40
#define FDIM    256     // NHEADS*NHID
#define HF      128     // channels per half
#define NBLK    ((NN+255)/256)   // 391

typedef unsigned short u16;
typedef __attribute__((ext_vector_type(8))) short bf16x8;
typedef __attribute__((ext_vector_type(4))) float f32x4;

__device__ __forceinline__ float b2f(u16 u){ union{uint32_t i; float f;} v; v.i=((uint32_t)u)<<16; return v.f; }
__device__ __forceinline__ float lof(uint32_t u){ union{uint32_t i; float f;} v; v.i=u<<16; return v.f; }
__device__ __forceinline__ float hif(uint32_t u){ union{uint32_t i; float f;} v; v.i=u&0xFFFF0000u; return v.f; }
__device__ __forceinline__ u16 f2b(float f){ union{float f; uint32_t i;} v; v.f=f; uint32_t x=v.i; return (u16)((x + 0x7FFFu + ((x>>16)&1u))>>16); }
__device__ __forceinline__ float lrelu(float e){ return e > 0.f ? e : 0.2f*e; }

// ---------------- W transpose+cast: Wt[c][k] = bf16(W[head][k][hid]) -------
__global__ __launch_bounds__(256) void k_transposeW(const float* __restrict__ W, u16* __restrict__ Wt){
  int i = blockIdx.x*256 + threadIdx.x;
  if (i >= FDIM*NFEATC) return;
  int c = i >> 7, k = i & 127;
  int head = c >> 5, hid = c & 31;
  Wt[c*NFEATC + k] = f2b(W[head*(NFEATC*NHIDC) + k*NHIDC + hid]);
}

// ---------------- GEMM1 via MFMA: h0 = x @ W  (bf16 out) -------------------
__global__ __launch_bounds__(256) void k_gemm1_mfma(const float* __restrict__ x, const u16* __restrict__ Wt,
                                                    u16* __restrict__ h0){
  int w = threadIdx.x >> 6, lane = threadIdx.x & 63;
  int nt = blockIdx.x;
  int m = lane & 15, q = lane >> 4;
  int row = nt*16 + m;
  int c0 = w*64;
  const float* xrow = x + (size_t)row*NFEATC;
  f32x4 acc0 = {0.f,0.f,0.f,0.f}, acc1 = {0.f,0.f,0.f,0.f};
  f32x4 acc2 = {0.f,0.f,0.f,0.f}, acc3 = {0.f,0.f,0.f,0.f};
  #pragma unroll
  for (int kk=0; kk<NFEATC; kk+=32){
    int ko = kk + q*8;
    float4 xa = *(const float4*)(xrow + ko);
    float4 xb = *(const float4*)(xrow + ko + 4);
    bf16x8 a;
    a[0]=(short)f2b(xa.x); a[1]=(short)f2b(xa.y); a[2]=(short)f2b(xa.z); a[3]=(short)f2b(xa.w);
    a[4]=(short)f2b(xb.x); a[5]=(short)f2b(xb.y); a[6]=(short)f2b(xb.z); a[7]=(short)f2b(xb.w);
    bf16x8 b0 = *(const bf16x8*)(Wt + (size_t)(c0 +  0 + m)*NFEATC + ko);
    bf16x8 b1 = *(const bf16x8*)(Wt + (size_t)(c0 + 16 + m)*NFEATC + ko);
    bf16x8 b2 = *(const bf16x8*)(Wt + (size_t)(c0 + 32 + m)*NFEATC + ko);
    bf16x8 b3 = *(const bf16x8*)(Wt + (size_t)(c0 + 48 + m)*NFEATC + ko);
    acc0 = __builtin_amdgcn_mfma_f32_16x16x32_bf16(a, b0, acc0, 0,0,0);
    acc1 = __builtin_amdgcn_mfma_f32_16x16x32_bf16(a, b1, acc1, 0,0,0);
    acc2 = __builtin_amdgcn_mfma_f32_16x16x32_bf16(a, b2, acc2, 0,0,0);
    acc3 = __builtin_amdgcn_mfma_f32_16x16x32_bf16(a, b3, acc3, 0,0,0);
  }
  #pragma unroll
  for (int r=0; r<4; r++){
    size_t base = (size_t)(nt*16 + q*4 + r)*FDIM + c0 + m;
    h0[base +  0] = f2b(acc0[r]);
    h0[base + 16] = f2b(acc1[r]);
    h0[base + 32] = f2b(acc2[r]);
    h0[base + 48] = f2b(acc3[r]);
  }
}

// ---------------- s,t per (node,head), bf16 --------------------------------
__global__ __launch_bounds__(256) void k_st(const u16* __restrict__ h0, const float* __restrict__ a_src,
                                            const float* __restrict__ a_dst, u16* __restrict__ s,
                                            u16* __restrict__ t_){
  int i = blockIdx.x*256 + threadIdx.x;
  if (i >= NN*NHEADSC) return;
  int n = i>>3, head = i&7;
  const u16* hp = h0 + (size_t)n*FDIM + head*NHIDC;
  const float* ap = a_src + head*NHIDC;
  const float* bp = a_dst + head*NHIDC;
  float ss=0.f, tt=0.f;
  #pragma unroll
  for (int j=0;j<NHIDC;j++){
    float h = b2f(hp[j]);
    ss = fmaf(h, ap[j], ss); tt = fmaf(h, bp[j], tt);
  }
  s[i]=f2b(ss); t_[i]=f2b(tt);
}

// ---------------- CSR build ------------------------------------------------
__global__ __launch_bounds__(256) void k_zero(int* __restrict__ p, int n){
  int i = blockIdx.x*256 + threadIdx.x;
  if (i < n) p[i] = 0;
}
__global__ __launch_bounds__(256) void k_zero_f(float* __restrict__ p, int n){
  int i = blockIdx.x*256 + threadIdx.x;
  if (i < n) p[i] = 0.f;
}
__global__ __launch_bounds__(256) void k_count(const int* __restrict__ dst, int* __restrict__ counts){
  int e = blockIdx.x*256 + threadIdx.x;
  if (e < EE) atomicAdd(&counts[dst[e]], 1);
}
__global__ __launch_bounds__(256) void k_blocksum(const int* __restrict__ counts, int* __restrict__ bsum){
  __shared__ int wsum[4];
  int b = blockIdx.x, t = threadIdx.x;
  int i = b*256 + t;
  int v = (i < NN) ? counts[i] : 0;
  #pragma unroll
  for (int off=32; off; off>>=1) v += __shfl_xor(v, off);
  if ((t & 63) == 0) wsum[t>>6] = v;
  __syncthreads();
  if (t == 0) bsum[b] = wsum[0]+wsum[1]+wsum[2]+wsum[3];
}
__global__ __launch_bounds__(512) void k_scan_bsum(const int* __restrict__ bsum, int* __restrict__ boff){
  __shared__ int lds[512];
  int t = threadIdx.x;
  int v = (t < NBLK) ? bsum[t] : 0;
  lds[t] = v; __syncthreads();
  for (int off=1; off<512; off<<=1){
    int u = (t>=off) ? lds[t-off] : 0;
    __syncthreads();
    lds[t] += u;
    __syncthreads();
  }
  if (t < NBLK) boff[t] = lds[t] - v;
}
__global__ __launch_bounds__(256) void k_scan_final(const int* __restrict__ counts, const int* __restrict__ boff,
                                                    int* __restrict__ row_start){
  __shared__ int lds[256];
  int b = blockIdx.x, t = threadIdx.x;
  int i = b*256 + t;
  int v = (i < NN) ? counts[i] : 0;
  lds[t] = v; __syncthreads();
  for (int off=1; off<256; off<<=1){
    int u = (t>=off) ? lds[t-off] : 0;
    __syncthreads();
    lds[t] += u;
    __syncthreads();
  }
  if (i < NN) row_start[i] = boff[b] + lds[t] - v;
  if (b == 0 && t == 0) row_start[NN] = EE;
}
__global__ __launch_bounds__(256) void k_scatter(const int* __restrict__ src, const int* __restrict__ dst,
                                                 const int* __restrict__ row_start, int* __restrict__ fill,
                                                 int* __restrict__ csr_src){
  int e = blockIdx.x*256 + threadIdx.x;
  if (e >= EE) return;
  int d = dst[e];
  int pos = row_start[d] + atomicAdd(&fill[d], 1);
  csr_src[pos] = src[e];
}

// ---------------- attention, all 8 heads: p_all (bf16) + inv-denominator ---
__global__ __launch_bounds__(256) void k_att(const u16* __restrict__ s, const u16* __restrict__ t_,
                                             const int* __restrict__ row_start, const int* __restrict__ csr_src,
                                             u16* __restrict__ p_all, float* __restrict__ scale){
  int i = blockIdx.x*256 + threadIdx.x;
  if (i >= NN*NHEADSC) return;
  int n = i>>3, head = i&7;
  int beg = row_start[n], end = row_start[n+1];
  float tn = b2f(t_[i]);
  float d0=0.f,d1=0.f,d2=0.f,d3=0.f;
  int pos = beg;
  for (; pos+4<=end; pos+=4){
    int u0=csr_src[pos], u1=csr_src[pos+1], u2=csr_src[pos+2], u3=csr_src[pos+3];
    float e0=lrelu(b2f(s[u0*NHEADSC+head])+tn);
    float e1=lrelu(b2f(s[u1*NHEADSC+head])+tn);
    float e2=lrelu(b2f(s[u2*NHEADSC+head])+tn);
    float e3=lrelu(b2f(s[u3*NHEADSC+head])+tn);
    u16 p0=f2b(__expf(e0)), p1=f2b(__expf(e1)), p2=f2b(__expf(e2)), p3=f2b(__expf(e3));
    p_all[(size_t)(pos+0)*NHEADSC+head]=p0;
    p_all[(size_t)(pos+1)*NHEADSC+head]=p1;
    p_all[(size_t)(pos+2)*NHEADSC+head]=p2;
    p_all[(size_t)(pos+3)*NHEADSC+head]=p3;
    d0+=b2f(p0); d1+=b2f(p1); d2+=b2f(p2); d3+=b2f(p3);
  }
  for (; pos<end; pos++){
    int u = csr_src[pos];
    float e = lrelu(b2f(s[u*NHEADSC+head])+tn);
    u16 pb = f2b(__expf(e));
    p_all[(size_t)pos*NHEADSC+head]=pb;
    d0 += b2f(pb);
  }
  scale[i] = 1.0f/(((d0+d1)+(d2+d3)) + 1e-16f);
}

// ---------------- hop1 (half): wave per node, 128 ch (2/lane), unroll x4 ---
__global__ __launch_bounds__(256) void k_hop1h(const u16* __restrict__ h0, const u16* __restrict__ p_all,
                                               const float* __restrict__ scale, const int* __restrict__ row_start,
                                               const int* __restrict__ csr_src, u16* __restrict__ featAh, int h){
  int wv = threadIdx.x >> 6, l = threadIdx.x & 63;
  int n = blockIdx.x*4 + wv;
  int head = h*4 + (l>>4);
  int cg = h*HF + 2*l;
  float sc_ = scale[n*NHEADSC + head];
  int beg = row_start[n], end = row_start[n+1];
  float x0=0.f,y0=0.f,x1=0.f,y1=0.f,x2=0.f,y2=0.f,x3=0.f,y3=0.f;
  int pos = beg;
  for (; pos+4<=end; pos+=4){
    int u0=csr_src[pos], u1=csr_src[pos+1], u2=csr_src[pos+2], u3=csr_src[pos+3];
    float p0=b2f(p_all[(size_t)(pos+0)*NHEADSC+head]);
    float p1=b2f(p_all[(size_t)(pos+1)*NHEADSC+head]);
    float p2=b2f(p_all[(size_t)(pos+2)*NHEADSC+head]);
    float p3=b2f(p_all[(size_t)(pos+3)*NHEADSC+head]);
    uint32_t g0 = *(const uint32_t*)(h0 + (size_t)u0*FDIM + cg);
    uint32_t g1 = *(const uint32_t*)(h0 + (size_t)u1*FDIM + cg);
    uint32_t g2 = *(const uint32_t*)(h0 + (size_t)u2*FDIM + cg);
    uint32_t g3 = *(const uint32_t*)(h0 + (size_t)u3*FDIM + cg);
    x0=fmaf(p0,lof(g0),x0); y0=fmaf(p0,hif(g0),y0);
    x1=fmaf(p1,lof(g1),x1); y1=fmaf(p1,hif(g1),y1);
    x2=fmaf(p2,lof(g2),x2); y2=fmaf(p2,hif(g2),y2);
    x3=fmaf(p3,lof(g3),x3); y3=fmaf(p3,hif(g3),y3);
  }
  for (; pos<end; pos++){
    int u=csr_src[pos];
    float p=b2f(p_all[(size_t)pos*NHEADSC+head]);
    uint32_t g = *(const uint32_t*)(h0 + (size_t)u*FDIM + cg);
    x0=fmaf(p,lof(g),x0); y0=fmaf(p,hif(g),y0);
  }
  float ax=(x0+x1)+(x2+x3), ay=(y0+y1)+(y2+y3);
  uint32_t hu = *(const uint32_t*)(h0 + (size_t)n*FDIM + cg);
  float rx = 0.9f*sc_*ax + 0.1f*lof(hu);
  float ry = 0.9f*sc_*ay + 0.1f*hif(hu);
  *(uint32_t*)(featAh + (size_t)n*HF + 2*l) = (uint32_t)f2b(rx) | ((uint32_t)f2b(ry)<<16);
}

// ---------------- hop2 (half) + elu + GEMM2 partial, unroll x4 -------------
__global__ __launch_bounds__(256) void k_hop2h(const u16* __restrict__ featAh, const u16* __restrict__ h0,
                                               const u16* __restrict__ p_all, const float* __restrict__ scale,
                                               const int* __restrict__ row_start, const int* __restrict__ csr_src,
                                               const float* __restrict__ W_out, float* __restrict__ out0, int h){
  __shared__ float hs[4][HF+2];   // +2 pad: node stride offsets banks
  int wv = threadIdx.x >> 6, l = threadIdx.x & 63;
  int n = blockIdx.x*4 + wv;
  int head = h*4 + (l>>4);
  int cg = h*HF + 2*l;
  float sc_ = scale[n*NHEADSC + head];
  int beg = row_start[n], end = row_start[n+1];
  float x0=0.f,y0=0.f,x1=0.f,y1=0.f,x2=0.f,y2=0.f,x3=0.f,y3=0.f;
  int pos = beg;
  for (; pos+4<=end; pos+=4){
    int u0=csr_src[pos], u1=csr_src[pos+1], u2=csr_src[pos+2], u3=csr_src[pos+3];
    float p0=b2f(p_all[(size_t)(pos+0)*NHEADSC+head]);
    float p1=b2f(p_all[(size_t)(pos+1)*NHEADSC+head]);
    float p2=b2f(p_all[(size_t)(pos+2)*NHEADSC+head]);
    float p3=b2f(p_all[(size_t)(pos+3)*NHEADSC+head]);
    uint32_t g0 = *(const uint32_t*)(featAh + (size_t)u0*HF + 2*l);
    uint32_t g1 = *(const uint32_t*)(featAh + (size_t)u1*HF + 2*l);
    uint32_t g2 = *(const uint32_t*)(featAh + (size_t)u2*HF + 2*l);
    uint32_t g3 = *(const uint32_t*)(featAh + (size_t)u3*HF + 2*l);
    x0=fmaf(p0,lof(g0),x0); y0=fmaf(p0,hif(g0),y0);
    x1=fmaf(p1,lof(g1),x1); y1=fmaf(p1,hif(g1),y1);
    x2=fmaf(p2,lof(g2),x2); y2=fmaf(p2,hif(g2),y2);
    x3=fmaf(p3,lof(g3),x3); y3=fmaf(p3,hif(g3),y3);
  }
  for (; pos<end; pos++){
    int u=csr_src[pos];
    float p=b2f(p_all[(size_t)pos*NHEADSC+head]);
    uint32_t g = *(const uint32_t*)(featAh + (size_t)u*HF + 2*l);
    x0=fmaf(p,lof(g),x0); y0=fmaf(p,hif(g),y0);
  }
  float ax=(x0+x1)+(x2+x3), ay=(y0+y1)+(y2+y3);
  uint32_t hu = *(const uint32_t*)(h0 + (size_t)n*FDIM + cg);
  float rx = 0.9f*sc_*ax + 0.1f*lof(hu);
  float ry = 0.9f*sc_*ay + 0.1f*hif(hu);
  hs[wv][2*l  ] = rx > 0.f ? rx : (__expf(rx)-1.0f);
  hs[wv][2*l+1] = ry > 0.f ? ry : (__expf(ry)-1.0f);
  __syncthreads();
  int t = threadIdx.x;
  if (t < 4*NCLASSC){
    int node = t/NCLASSC, c = t%NCLASSC;
    const float* hv = hs[node];
    const float* wp = W_out + (size_t)(h*HF)*NCLASSC + c;
    float o = 0.f;
    #pragma unroll 8
    for (int k=0;k<HF;k++) o = fmaf(hv[k], wp[(size_t)k*NCLASSC], o);
    out0[(size_t)(blockIdx.x*4+node)*NCLASSC + c] += o;   // halves stream-serialized
  }
}

// ---------------- output-layer s,t -----------------------------------------
__global__ __launch_bounds__(256) void k_st_out(const float* __restrict__ out0, const float* __restrict__ a_s,
                                                const float* __restrict__ a_d, float* __restrict__ s,
                                                float* __restrict__ t_){
  int n = blockIdx.x*256 + threadIdx.x;
  if (n >= NN) return;
  const float* r = out0 + (size_t)n*NCLASSC;
  float ss=0.f, tt=0.f;
  for (int c=0;c<NCLASSC;c++){ float v=r[c]; ss=fmaf(v,a_s[c],ss); tt=fmaf(v,a_d[c],tt); }
  s[n]=ss; t_[n]=tt;
}

// ---------------- output-layer attention: p (fp32), unroll x4 --------------
__global__ __launch_bounds__(256) void k_att_out(const float* __restrict__ s, const float* __restrict__ t_,
                                                 const int* __restrict__ row_start, const int* __restrict__ csr_src,
                                                 float* __restrict__ p_out, float* __restrict__ scale_out){
  int n = blockIdx.x*256 + threadIdx.x;
  if (n >= NN) return;
  int beg = row_start[n], end = row_start[n+1];
  float tn = t_[n];
  float d0=0.f,d1=0.f,d2=0.f,d3=0.f;
  int pos = beg;
  for (; pos+4<=end; pos+=4){
    int u0=csr_src[pos], u1=csr_src[pos+1], u2=csr_src[pos+2], u3=csr_src[pos+3];
    float p0=__expf(lrelu(s[u0]+tn));
    float p1=__expf(lrelu(s[u1]+tn));
    float p2=__expf(lrelu(s[u2]+tn));
    float p3=__expf(lrelu(s[u3]+tn));
    p_out[pos]=p0; p_out[pos+1]=p1; p_out[pos+2]=p2; p_out[pos+3]=p3;
    d0+=p0; d1+=p1; d2+=p2; d3+=p3;
  }
  for (; pos<end; pos++){
    float p = __expf(lrelu(s[csr_src[pos]]+tn));
    p_out[pos] = p;
    d0 += p;
  }
  scale_out[n] = 1.0f/(((d0+d1)+(d2+d3)) + 1e-16f);
}

// ---------------- output-layer hop 1, unroll x4 ----------------------------
__global__ __launch_bounds__(64) void k_hop1_out(const float* __restrict__ out0, const float* __restrict__ p_out,
                                                 const float* __restrict__ scale_out, const int* __restrict__ row_start,
                                                 const int* __restrict__ csr_src, u16* __restrict__ outA){
  int n = blockIdx.x, t = threadIdx.x;
  float sc_ = scale_out[n];
  int beg = row_start[n], end = row_start[n+1];
  int tc = (t < NCLASSC) ? t : 0;
  float a0=0.f,a1=0.f,a2=0.f,a3=0.f;
  int pos = beg;
  for (; pos+4<=end; pos+=4){
    int u0=csr_src[pos], u1=csr_src[pos+1], u2=csr_src[pos+2], u3=csr_src[pos+3];
    float p0=p_out[pos], p1=p_out[pos+1], p2=p_out[pos+2], p3=p_out[pos+3];
    float f0=out0[(size_t)u0*NCLASSC+tc];
    float f1=out0[(size_t)u1*NCLASSC+tc];
    float f2=out0[(size_t)u2*NCLASSC+tc];
    float f3=out0[(size_t)u3*NCLASSC+tc];
    a0=fmaf(p0,f0,a0); a1=fmaf(p1,f1,a1); a2=fmaf(p2,f2,a2); a3=fmaf(p3,f3,a3);
  }
  for (; pos<end; pos++){
    a0=fmaf(p_out[pos], out0[(size_t)csr_src[pos]*NCLASSC+tc], a0);
  }
  if (t < NCLASSC){
    float res = 0.9f*sc_*((a0+a1)+(a2+a3)) + 0.1f*out0[(size_t)n*NCLASSC + t];
    outA[(size_t)n*NCLASSC + t] = f2b(res);
  }
}

// ---------------- output-layer hop 2 + elu + log_softmax, unroll x4 --------
__global__ __launch_bounds__(64) void k_hop2_out_final(const u16* __restrict__ outA, const float* __restrict__ out0,
                                                       const float* __restrict__ p_out, const float* __restrict__ scale_out,
                                                       const int* __restrict__ row_start, const int* __restrict__ csr_src,
                                                       float* __restrict__ out){
  int n = blockIdx.x, t = threadIdx.x;
  float sc_ = scale_out[n];
  int beg = row_start[n], end = row_start[n+1];
  int tc = (t < NCLASSC) ? t : 0;
  float a0=0.f,a1=0.f,a2=0.f,a3=0.f;
  int pos = beg;
  for (; pos+4<=end; pos+=4){
    int u0=csr_src[pos], u1=csr_src[pos+1], u2=csr_src[pos+2], u3=csr_src[pos+3];
    float p0=p_out[pos], p1=p_out[pos+1], p2=p_out[pos+2], p3=p_out[pos+3];
    float f0=b2f(outA[(size_t)u0*NCLASSC+tc]);
    float f1=b2f(outA[(size_t)u1*NCLASSC+tc]);
    float f2=b2f(outA[(size_t)u2*NCLASSC+tc]);
    float f3=b2f(outA[(size_t)u3*NCLASSC+tc]);
    a0=fmaf(p0,f0,a0); a1=fmaf(p1,f1,a1); a2=fmaf(p2,f2,a2); a3=fmaf(p3,f3,a3);
  }
  for (; pos<end; pos++){
    a0=fmaf(p_out[pos], b2f(outA[(size_t)csr_src[pos]*NCLASSC+tc]), a0);
  }
  float v = -1e30f;
  if (t < NCLASSC){
    float res = 0.9f*sc_*((a0+a1)+(a2+a3)) + 0.1f*out0[(size_t)n*NCLASSC + t];
    v = res > 0.f ? res : (__expf(res)-1.0f);
  }
  float m = v;
  #pragma unroll
  for (int off=32; off; off>>=1) m = fmaxf(m, __shfl_xor(m, off));
  float ex = (t < NCLASSC) ? __expf(v - m) : 0.f;
  float ssum = ex;
  #pragma unroll
  for (int off=32; off; off>>=1) ssum += __shfl_xor(ssum, off);
  if (t < NCLASSC) out[(size_t)n*NCLASSC + t] = v - m - __logf(ssum);
}

extern "C" void kernel_launch(void* const* d_in, const int* in_sizes, int n_in,
                              void* d_out, int out_size, void* d_ws, size_t ws_size,
                              hipStream_t stream){
  const float* x        = (const float*)d_in[0];
  const int*   ei       = (const int*)d_in[1];
  const float* W        = (const float*)d_in[2];
  const float* a_src    = (const float*)d_in[3];
  const float* a_dst    = (const float*)d_in[4];
  const float* W_out    = (const float*)d_in[5];
  const float* a_src_o  = (const float*)d_in[6];
  const float* a_dst_o  = (const float*)d_in[7];
  float* out            = (float*)d_out;
  const int* e_src = ei;
  const int* e_dst = ei + EE;

  // ---- workspace: ~141 MB (<=157 MB proven safe) ----
  char* ws = (char*)d_ws;
  size_t off = 0;
  auto alloc = [&](size_t bytes)->char*{ char* p = ws + off; off += (bytes + 255) & ~(size_t)255; return p; };

  u16*   h0        = (u16*)  alloc((size_t)NN*FDIM*2);      // 51.2 MB
  u16*   featAh    = (u16*)  alloc((size_t)NN*HF*2);        // 25.6 MB
  float* out0      = (float*)alloc((size_t)NN*NCLASSC*4);   // 16 MB
  int*   csr_src   = (int*)  alloc((size_t)EE*4);           // 6.4 MB
  int*   row_start = (int*)  alloc((size_t)(NN+1)*4);       // 0.4 MB
  u16*   s         = (u16*)  alloc((size_t)NN*NHEADSC*2);   // 1.6 MB
  u16*   t_        = (u16*)  alloc((size_t)NN*NHEADSC*2);   // 1.6 MB
  u16*   p_all     = (u16*)  alloc((size_t)EE*NHEADSC*2);   // 25.6 MB (bf16; fp32 p_out aliased later)
  float* scale     = (float*)alloc((size_t)NN*NHEADSC*4);   // 3.2 MB
  u16*   outA      = (u16*)  alloc((size_t)NN*NCLASSC*2);   // 8 MB
  float* s_out     = (float*)alloc((size_t)NN*4);
  float* t_out     = (float*)alloc((size_t)NN*4);
  float* scale_out = (float*)alloc((size_t)NN*4);
  int*   counts    = (int*)  alloc((size_t)NN*4);
  int*   bsum      = (int*)  alloc((size_t)NBLK*4);
  int*   boff      = (int*)  alloc((size_t)NBLK*4);
  u16*   Wt        = (u16*)  alloc((size_t)FDIM*NFEATC*2);
  float* p_out     = (float*)p_all;                         // alias: p_all dead after phase 3

  // phase 1: feature transform (MFMA) + per-head s,t
  k_transposeW<<<(FDIM*NFEATC+255)/256, 256, 0, stream>>>(W, Wt);
  k_gemm1_mfma<<<NN/16, 256, 0, stream>>>(x, Wt, h0);
  k_st<<<(NN*NHEADSC+255)/256, 256, 0, stream>>>(h0, a_src, a_dst, s, t_);

  // phase 2: CSR build (hierarchical scan)
  k_zero<<<(NN+255)/256, 256, 0, stream>>>(counts, NN);
  k_count<<<(EE+255)/256, 256, 0, stream>>>(e_dst, counts);
  k_blocksum<<<NBLK, 256, 0, stream>>>(counts, bsum);
  k_scan_bsum<<<1, 512, 0, stream>>>(bsum, boff);
  k_scan_final<<<NBLK, 256, 0, stream>>>(counts, boff, row_start);
  k_zero<<<(NN+255)/256, 256, 0, stream>>>(counts, NN);
  k_scatter<<<(EE+255)/256, 256, 0, stream>>>(e_src, e_dst, row_start, counts, csr_src);

  // phase 3: single attention pass (all heads), then per-half hops
  k_att<<<(NN*NHEADSC+255)/256, 256, 0, stream>>>(s, t_, row_start, csr_src, p_all, scale);
  k_zero_f<<<(NN*NCLASSC+255)/256, 256, 0, stream>>>(out0, NN*NCLASSC);
  for (int h=0; h<2; h++){
    k_hop1h<<<NN/4, 256, 0, stream>>>(h0, p_all, scale, row_start, csr_src, featAh, h);
    k_hop2h<<<NN/4, 256, 0, stream>>>(featAh, h0, p_all, scale, row_start, csr_src, W_out, out0, h);
  }

  // phase 4: output layer (p precomputed fp32, aliased into p_all)
  k_st_out<<<(NN+255)/256, 256, 0, stream>>>(out0, a_src_o, a_dst_o, s_out, t_out);
  k_att_out<<<(NN+255)/256, 256, 0, stream>>>(s_out, t_out, row_start, csr_src, p_out, scale_out);
  k_hop1_out<<<NN, 64, 0, stream>>>(out0, p_out, scale_out, row_start, csr_src, outA);
  k_hop2_out_final<<<NN, 64, 0, stream>>>(outA, out0, p_out, scale_out, row_start, csr_src, out);
}

// Round 10
// 877.441 us; speedup vs baseline: 2.8584x; 1.0791x over previous
//
#include <hip/hip_runtime.h>
#include <hip/hip_fp16.h>
#include <stdint.h>

#define NN      100000
#define EE      1600000
#define NFEATC  128
#define NHIDC   32
#define NHEADSC 8
#define NCLASSC 40
#define FDIM    256     // NHEADS*NHID
#define NBLK    ((NN+255)/256)   // 391

typedef unsigned short u16;
typedef __attribute__((ext_vector_type(8))) short bf16x8;
typedef __attribute__((ext_vector_type(4))) float f32x4;

__device__ __forceinline__ float b2f(u16 u){ union{uint32_t i; float f;} v; v.i=((uint32_t)u)<<16; return v.f; }
__device__ __forceinline__ float lof(uint32_t u){ union{uint32_t i; float f;} v; v.i=u<<16; return v.f; }
__device__ __forceinline__ float hif(uint32_t u){ union{uint32_t i; float f;} v; v.i=u&0xFFFF0000u; return v.f; }
__device__ __forceinline__ u16 f2b(float f){ union{float f; uint32_t i;} v; v.f=f; uint32_t x=v.i; return (u16)((x + 0x7FFFu + ((x>>16)&1u))>>16); }
__device__ __forceinline__ uint32_t pack2(float a, float b){ return (uint32_t)f2b(a) | ((uint32_t)f2b(b)<<16); }
__device__ __forceinline__ float lrelu(float e){ return e > 0.f ? e : 0.2f*e; }

// ---------------- W transpose+cast: Wt[c][k] = bf16(W[head][k][hid]) -------
__global__ __launch_bounds__(256) void k_transposeW(const float* __restrict__ W, u16* __restrict__ Wt){
  int i = blockIdx.x*256 + threadIdx.x;
  if (i >= FDIM*NFEATC) return;
  int c = i >> 7, k = i & 127;
  int head = c >> 5, hid = c & 31;
  Wt[c*NFEATC + k] = f2b(W[head*(NFEATC*NHIDC) + k*NHIDC + hid]);
}

// ---------------- GEMM1 via MFMA: h0 = x @ W  (bf16 out) -------------------
__global__ __launch_bounds__(256) void k_gemm1_mfma(const float* __restrict__ x, const u16* __restrict__ Wt,
                                                    u16* __restrict__ h0){
  int w = threadIdx.x >> 6, lane = threadIdx.x & 63;
  int nt = blockIdx.x;
  int m = lane & 15, q = lane >> 4;
  int row = nt*16 + m;
  int c0 = w*64;
  const float* xrow = x + (size_t)row*NFEATC;
  f32x4 acc0 = {0.f,0.f,0.f,0.f}, acc1 = {0.f,0.f,0.f,0.f};
  f32x4 acc2 = {0.f,0.f,0.f,0.f}, acc3 = {0.f,0.f,0.f,0.f};
  #pragma unroll
  for (int kk=0; kk<NFEATC; kk+=32){
    int ko = kk + q*8;
    float4 xa = *(const float4*)(xrow + ko);
    float4 xb = *(const float4*)(xrow + ko + 4);
    bf16x8 a;
    a[0]=(short)f2b(xa.x); a[1]=(short)f2b(xa.y); a[2]=(short)f2b(xa.z); a[3]=(short)f2b(xa.w);
    a[4]=(short)f2b(xb.x); a[5]=(short)f2b(xb.y); a[6]=(short)f2b(xb.z); a[7]=(short)f2b(xb.w);
    bf16x8 b0 = *(const bf16x8*)(Wt + (size_t)(c0 +  0 + m)*NFEATC + ko);
    bf16x8 b1 = *(const bf16x8*)(Wt + (size_t)(c0 + 16 + m)*NFEATC + ko);
    bf16x8 b2 = *(const bf16x8*)(Wt + (size_t)(c0 + 32 + m)*NFEATC + ko);
    bf16x8 b3 = *(const bf16x8*)(Wt + (size_t)(c0 + 48 + m)*NFEATC + ko);
    acc0 = __builtin_amdgcn_mfma_f32_16x16x32_bf16(a, b0, acc0, 0,0,0);
    acc1 = __builtin_amdgcn_mfma_f32_16x16x32_bf16(a, b1, acc1, 0,0,0);
    acc2 = __builtin_amdgcn_mfma_f32_16x16x32_bf16(a, b2, acc2, 0,0,0);
    acc3 = __builtin_amdgcn_mfma_f32_16x16x32_bf16(a, b3, acc3, 0,0,0);
  }
  #pragma unroll
  for (int r=0; r<4; r++){
    size_t base = (size_t)(nt*16 + q*4 + r)*FDIM + c0 + m;
    h0[base +  0] = f2b(acc0[r]);
    h0[base + 16] = f2b(acc1[r]);
    h0[base + 32] = f2b(acc2[r]);
    h0[base + 48] = f2b(acc3[r]);
  }
}

// ---------------- s,t per (node,head), bf16 --------------------------------
__global__ __launch_bounds__(256) void k_st(const u16* __restrict__ h0, const float* __restrict__ a_src,
                                            const float* __restrict__ a_dst, u16* __restrict__ s,
                                            u16* __restrict__ t_){
  int i = blockIdx.x*256 + threadIdx.x;
  if (i >= NN*NHEADSC) return;
  int n = i>>3, head = i&7;
  const u16* hp = h0 + (size_t)n*FDIM + head*NHIDC;
  const float* ap = a_src + head*NHIDC;
  const float* bp = a_dst + head*NHIDC;
  float ss=0.f, tt=0.f;
  #pragma unroll
  for (int j=0;j<NHIDC;j++){
    float h = b2f(hp[j]);
    ss = fmaf(h, ap[j], ss); tt = fmaf(h, bp[j], tt);
  }
  s[i]=f2b(ss); t_[i]=f2b(tt);
}

// ---------------- CSR build ------------------------------------------------
__global__ __launch_bounds__(256) void k_zero(int* __restrict__ p, int n){
  int i = blockIdx.x*256 + threadIdx.x;
  if (i < n) p[i] = 0;
}
__global__ __launch_bounds__(256) void k_zero_f(float* __restrict__ p, int n){
  int i = blockIdx.x*256 + threadIdx.x;
  if (i < n) p[i] = 0.f;
}
__global__ __launch_bounds__(256) void k_count(const int* __restrict__ dst, int* __restrict__ counts){
  int e = blockIdx.x*256 + threadIdx.x;
  if (e < EE) atomicAdd(&counts[dst[e]], 1);
}
__global__ __launch_bounds__(256) void k_blocksum(const int* __restrict__ counts, int* __restrict__ bsum){
  __shared__ int wsum[4];
  int b = blockIdx.x, t = threadIdx.x;
  int i = b*256 + t;
  int v = (i < NN) ? counts[i] : 0;
  #pragma unroll
  for (int off=32; off; off>>=1) v += __shfl_xor(v, off);
  if ((t & 63) == 0) wsum[t>>6] = v;
  __syncthreads();
  if (t == 0) bsum[b] = wsum[0]+wsum[1]+wsum[2]+wsum[3];
}
__global__ __launch_bounds__(512) void k_scan_bsum(const int* __restrict__ bsum, int* __restrict__ boff){
  __shared__ int lds[512];
  int t = threadIdx.x;
  int v = (t < NBLK) ? bsum[t] : 0;
  lds[t] = v; __syncthreads();
  for (int off=1; off<512; off<<=1){
    int u = (t>=off) ? lds[t-off] : 0;
    __syncthreads();
    lds[t] += u;
    __syncthreads();
  }
  if (t < NBLK) boff[t] = lds[t] - v;
}
__global__ __launch_bounds__(256) void k_scan_final(const int* __restrict__ counts, const int* __restrict__ boff,
                                                    int* __restrict__ row_start){
  __shared__ int lds[256];
  int b = blockIdx.x, t = threadIdx.x;
  int i = b*256 + t;
  int v = (i < NN) ? counts[i] : 0;
  lds[t] = v; __syncthreads();
  for (int off=1; off<256; off<<=1){
    int u = (t>=off) ? lds[t-off] : 0;
    __syncthreads();
    lds[t] += u;
    __syncthreads();
  }
  if (i < NN) row_start[i] = boff[b] + lds[t] - v;
  if (b == 0 && t == 0) row_start[NN] = EE;
}
__global__ __launch_bounds__(256) void k_scatter(const int* __restrict__ src, const int* __restrict__ dst,
                                                 const int* __restrict__ row_start, int* __restrict__ fill,
                                                 int* __restrict__ csr_src){
  int e = blockIdx.x*256 + threadIdx.x;
  if (e >= EE) return;
  int d = dst[e];
  int pos = row_start[d] + atomicAdd(&fill[d], 1);
  csr_src[pos] = src[e];
}

// ---------------- attention, all 8 heads: p_all (bf16) + 1/denom (fp16) ----
__global__ __launch_bounds__(256) void k_att(const u16* __restrict__ s, const u16* __restrict__ t_,
                                             const int* __restrict__ row_start, const int* __restrict__ csr_src,
                                             u16* __restrict__ p_all, __half* __restrict__ scale){
  int i = blockIdx.x*256 + threadIdx.x;
  if (i >= NN*NHEADSC) return;
  int n = i>>3, head = i&7;
  int beg = row_start[n], end = row_start[n+1];
  float tn = b2f(t_[i]);
  float d0=0.f,d1=0.f,d2=0.f,d3=0.f;
  int pos = beg;
  for (; pos+4<=end; pos+=4){
    int u0=csr_src[pos], u1=csr_src[pos+1], u2=csr_src[pos+2], u3=csr_src[pos+3];
    float e0=lrelu(b2f(s[u0*NHEADSC+head])+tn);
    float e1=lrelu(b2f(s[u1*NHEADSC+head])+tn);
    float e2=lrelu(b2f(s[u2*NHEADSC+head])+tn);
    float e3=lrelu(b2f(s[u3*NHEADSC+head])+tn);
    u16 p0=f2b(__expf(e0)), p1=f2b(__expf(e1)), p2=f2b(__expf(e2)), p3=f2b(__expf(e3));
    p_all[(size_t)(pos+0)*NHEADSC+head]=p0;
    p_all[(size_t)(pos+1)*NHEADSC+head]=p1;
    p_all[(size_t)(pos+2)*NHEADSC+head]=p2;
    p_all[(size_t)(pos+3)*NHEADSC+head]=p3;
    d0+=b2f(p0); d1+=b2f(p1); d2+=b2f(p2); d3+=b2f(p3);
  }
  for (; pos<end; pos++){
    int u = csr_src[pos];
    float e = lrelu(b2f(s[u*NHEADSC+head])+tn);
    u16 pb = f2b(__expf(e));
    p_all[(size_t)pos*NHEADSC+head]=pb;
    d0 += b2f(pb);
  }
  scale[i] = __float2half(1.0f/(((d0+d1)+(d2+d3)) + 1e-16f));
}

// ---------------- hop1 full row: wave/node, 256 ch (4/lane), unroll x4 -----
__global__ __launch_bounds__(256) void k_hop1(const u16* __restrict__ h0, const u16* __restrict__ p_all,
                                              const __half* __restrict__ scale, const int* __restrict__ row_start,
                                              const int* __restrict__ csr_src, u16* __restrict__ featA){
  int wv = threadIdx.x >> 6, l = threadIdx.x & 63;
  int n = blockIdx.x*4 + wv;
  int head = l >> 3;                 // 4*l channel base -> head = (4l)>>5
  int cg = 4*l;
  float sc_ = __half2float(scale[n*NHEADSC + head]);
  int beg = row_start[n], end = row_start[n+1];
  float a0=0.f,b0a=0.f,c0a=0.f,d0a=0.f, a1=0.f,b1a=0.f,c1a=0.f,d1a=0.f;
  float a2=0.f,b2a=0.f,c2a=0.f,d2a=0.f, a3=0.f,b3a=0.f,c3a=0.f,d3a=0.f;
  int pos = beg;
  for (; pos+4<=end; pos+=4){
    int u0=csr_src[pos], u1=csr_src[pos+1], u2=csr_src[pos+2], u3=csr_src[pos+3];
    float p0=b2f(p_all[(size_t)(pos+0)*NHEADSC+head]);
    float p1=b2f(p_all[(size_t)(pos+1)*NHEADSC+head]);
    float p2=b2f(p_all[(size_t)(pos+2)*NHEADSC+head]);
    float p3=b2f(p_all[(size_t)(pos+3)*NHEADSC+head]);
    uint2 g0 = *(const uint2*)(h0 + (size_t)u0*FDIM + cg);
    uint2 g1 = *(const uint2*)(h0 + (size_t)u1*FDIM + cg);
    uint2 g2 = *(const uint2*)(h0 + (size_t)u2*FDIM + cg);
    uint2 g3 = *(const uint2*)(h0 + (size_t)u3*FDIM + cg);
    a0=fmaf(p0,lof(g0.x),a0); b0a=fmaf(p0,hif(g0.x),b0a); c0a=fmaf(p0,lof(g0.y),c0a); d0a=fmaf(p0,hif(g0.y),d0a);
    a1=fmaf(p1,lof(g1.x),a1); b1a=fmaf(p1,hif(g1.x),b1a); c1a=fmaf(p1,lof(g1.y),c1a); d1a=fmaf(p1,hif(g1.y),d1a);
    a2=fmaf(p2,lof(g2.x),a2); b2a=fmaf(p2,hif(g2.x),b2a); c2a=fmaf(p2,lof(g2.y),c2a); d2a=fmaf(p2,hif(g2.y),d2a);
    a3=fmaf(p3,lof(g3.x),a3); b3a=fmaf(p3,hif(g3.x),b3a); c3a=fmaf(p3,lof(g3.y),c3a); d3a=fmaf(p3,hif(g3.y),d3a);
  }
  for (; pos<end; pos++){
    int u=csr_src[pos];
    float p=b2f(p_all[(size_t)pos*NHEADSC+head]);
    uint2 g = *(const uint2*)(h0 + (size_t)u*FDIM + cg);
    a0=fmaf(p,lof(g.x),a0); b0a=fmaf(p,hif(g.x),b0a); c0a=fmaf(p,lof(g.y),c0a); d0a=fmaf(p,hif(g.y),d0a);
  }
  float ax=(a0+a1)+(a2+a3), ay=(b0a+b1a)+(b2a+b3a);
  float az=(c0a+c1a)+(c2a+c3a), aw=(d0a+d1a)+(d2a+d3a);
  uint2 hu = *(const uint2*)(h0 + (size_t)n*FDIM + cg);
  float rx = 0.9f*sc_*ax + 0.1f*lof(hu.x);
  float ry = 0.9f*sc_*ay + 0.1f*hif(hu.x);
  float rz = 0.9f*sc_*az + 0.1f*lof(hu.y);
  float rw = 0.9f*sc_*aw + 0.1f*hif(hu.y);
  uint2 o; o.x = pack2(rx,ry); o.y = pack2(rz,rw);
  *(uint2*)(featA + (size_t)n*FDIM + cg) = o;
}

// ---------------- hop2 full row + elu + GEMM2, unroll x4 -------------------
__global__ __launch_bounds__(256) void k_hop2(const u16* __restrict__ featA, const u16* __restrict__ h0,
                                              const u16* __restrict__ p_all, const __half* __restrict__ scale,
                                              const int* __restrict__ row_start, const int* __restrict__ csr_src,
                                              const float* __restrict__ W_out, float* __restrict__ out0){
  __shared__ float hs[4][FDIM+4];
  int wv = threadIdx.x >> 6, l = threadIdx.x & 63;
  int n = blockIdx.x*4 + wv;
  int head = l >> 3;
  int cg = 4*l;
  float sc_ = __half2float(scale[n*NHEADSC + head]);
  int beg = row_start[n], end = row_start[n+1];
  float a0=0.f,b0a=0.f,c0a=0.f,d0a=0.f, a1=0.f,b1a=0.f,c1a=0.f,d1a=0.f;
  float a2=0.f,b2a=0.f,c2a=0.f,d2a=0.f, a3=0.f,b3a=0.f,c3a=0.f,d3a=0.f;
  int pos = beg;
  for (; pos+4<=end; pos+=4){
    int u0=csr_src[pos], u1=csr_src[pos+1], u2=csr_src[pos+2], u3=csr_src[pos+3];
    float p0=b2f(p_all[(size_t)(pos+0)*NHEADSC+head]);
    float p1=b2f(p_all[(size_t)(pos+1)*NHEADSC+head]);
    float p2=b2f(p_all[(size_t)(pos+2)*NHEADSC+head]);
    float p3=b2f(p_all[(size_t)(pos+3)*NHEADSC+head]);
    uint2 g0 = *(const uint2*)(featA + (size_t)u0*FDIM + cg);
    uint2 g1 = *(const uint2*)(featA + (size_t)u1*FDIM + cg);
    uint2 g2 = *(const uint2*)(featA + (size_t)u2*FDIM + cg);
    uint2 g3 = *(const uint2*)(featA + (size_t)u3*FDIM + cg);
    a0=fmaf(p0,lof(g0.x),a0); b0a=fmaf(p0,hif(g0.x),b0a); c0a=fmaf(p0,lof(g0.y),c0a); d0a=fmaf(p0,hif(g0.y),d0a);
    a1=fmaf(p1,lof(g1.x),a1); b1a=fmaf(p1,hif(g1.x),b1a); c1a=fmaf(p1,lof(g1.y),c1a); d1a=fmaf(p1,hif(g1.y),d1a);
    a2=fmaf(p2,lof(g2.x),a2); b2a=fmaf(p2,hif(g2.x),b2a); c2a=fmaf(p2,lof(g2.y),c2a); d2a=fmaf(p2,hif(g2.y),d2a);
    a3=fmaf(p3,lof(g3.x),a3); b3a=fmaf(p3,hif(g3.x),b3a); c3a=fmaf(p3,lof(g3.y),c3a); d3a=fmaf(p3,hif(g3.y),d3a);
  }
  for (; pos<end; pos++){
    int u=csr_src[pos];
    float p=b2f(p_all[(size_t)pos*NHEADSC+head]);
    uint2 g = *(const uint2*)(featA + (size_t)u*FDIM + cg);
    a0=fmaf(p,lof(g.x),a0); b0a=fmaf(p,hif(g.x),b0a); c0a=fmaf(p,lof(g.y),c0a); d0a=fmaf(p,hif(g.y),d0a);
  }
  float ax=(a0+a1)+(a2+a3), ay=(b0a+b1a)+(b2a+b3a);
  float az=(c0a+c1a)+(c2a+c3a), aw=(d0a+d1a)+(d2a+d3a);
  uint2 hu = *(const uint2*)(h0 + (size_t)n*FDIM + cg);
  float rx = 0.9f*sc_*ax + 0.1f*lof(hu.x);
  float ry = 0.9f*sc_*ay + 0.1f*hif(hu.x);
  float rz = 0.9f*sc_*az + 0.1f*lof(hu.y);
  float rw = 0.9f*sc_*aw + 0.1f*hif(hu.y);
  hs[wv][cg  ] = rx > 0.f ? rx : (__expf(rx)-1.0f);
  hs[wv][cg+1] = ry > 0.f ? ry : (__expf(ry)-1.0f);
  hs[wv][cg+2] = rz > 0.f ? rz : (__expf(rz)-1.0f);
  hs[wv][cg+3] = rw > 0.f ? rw : (__expf(rw)-1.0f);
  __syncthreads();
  int t = threadIdx.x;
  if (t < 4*NCLASSC){
    int node = t/NCLASSC, c = t%NCLASSC;
    const float* hv = hs[node];
    const float* wp = W_out + c;
    float o = 0.f;
    #pragma unroll 8
    for (int k=0;k<FDIM;k++) o = fmaf(hv[k], wp[(size_t)k*NCLASSC], o);
    out0[(size_t)(blockIdx.x*4+node)*NCLASSC + c] = o;
  }
}

// ---------------- output-layer s,t -----------------------------------------
__global__ __launch_bounds__(256) void k_st_out(const float* __restrict__ out0, const float* __restrict__ a_s,
                                                const float* __restrict__ a_d, float* __restrict__ s,
                                                float* __restrict__ t_){
  int n = blockIdx.x*256 + threadIdx.x;
  if (n >= NN) return;
  const float* r = out0 + (size_t)n*NCLASSC;
  float ss=0.f, tt=0.f;
  for (int c=0;c<NCLASSC;c++){ float v=r[c]; ss=fmaf(v,a_s[c],ss); tt=fmaf(v,a_d[c],tt); }
  s[n]=ss; t_[n]=tt;
}

// ---------------- output-layer attention: p (fp32), unroll x4 --------------
__global__ __launch_bounds__(256) void k_att_out(const float* __restrict__ s, const float* __restrict__ t_,
                                                 const int* __restrict__ row_start, const int* __restrict__ csr_src,
                                                 float* __restrict__ p_out, float* __restrict__ scale_out){
  int n = blockIdx.x*256 + threadIdx.x;
  if (n >= NN) return;
  int beg = row_start[n], end = row_start[n+1];
  float tn = t_[n];
  float d0=0.f,d1=0.f,d2=0.f,d3=0.f;
  int pos = beg;
  for (; pos+4<=end; pos+=4){
    int u0=csr_src[pos], u1=csr_src[pos+1], u2=csr_src[pos+2], u3=csr_src[pos+3];
    float p0=__expf(lrelu(s[u0]+tn));
    float p1=__expf(lrelu(s[u1]+tn));
    float p2=__expf(lrelu(s[u2]+tn));
    float p3=__expf(lrelu(s[u3]+tn));
    p_out[pos]=p0; p_out[pos+1]=p1; p_out[pos+2]=p2; p_out[pos+3]=p3;
    d0+=p0; d1+=p1; d2+=p2; d3+=p3;
  }
  for (; pos<end; pos++){
    float p = __expf(lrelu(s[csr_src[pos]]+tn));
    p_out[pos] = p;
    d0 += p;
  }
  scale_out[n] = 1.0f/(((d0+d1)+(d2+d3)) + 1e-16f);
}

// ---------------- output-layer hop 1, unroll x4 ----------------------------
__global__ __launch_bounds__(64) void k_hop1_out(const float* __restrict__ out0, const float* __restrict__ p_out,
                                                 const float* __restrict__ scale_out, const int* __restrict__ row_start,
                                                 const int* __restrict__ csr_src, u16* __restrict__ outA){
  int n = blockIdx.x, t = threadIdx.x;
  float sc_ = scale_out[n];
  int beg = row_start[n], end = row_start[n+1];
  int tc = (t < NCLASSC) ? t : 0;
  float a0=0.f,a1=0.f,a2=0.f,a3=0.f;
  int pos = beg;
  for (; pos+4<=end; pos+=4){
    int u0=csr_src[pos], u1=csr_src[pos+1], u2=csr_src[pos+2], u3=csr_src[pos+3];
    float p0=p_out[pos], p1=p_out[pos+1], p2=p_out[pos+2], p3=p_out[pos+3];
    float f0=out0[(size_t)u0*NCLASSC+tc];
    float f1=out0[(size_t)u1*NCLASSC+tc];
    float f2=out0[(size_t)u2*NCLASSC+tc];
    float f3=out0[(size_t)u3*NCLASSC+tc];
    a0=fmaf(p0,f0,a0); a1=fmaf(p1,f1,a1); a2=fmaf(p2,f2,a2); a3=fmaf(p3,f3,a3);
  }
  for (; pos<end; pos++){
    a0=fmaf(p_out[pos], out0[(size_t)csr_src[pos]*NCLASSC+tc], a0);
  }
  if (t < NCLASSC){
    float res = 0.9f*sc_*((a0+a1)+(a2+a3)) + 0.1f*out0[(size_t)n*NCLASSC + t];
    outA[(size_t)n*NCLASSC + t] = f2b(res);
  }
}

// ---------------- output-layer hop 2 + elu + log_softmax, unroll x4 --------
__global__ __launch_bounds__(64) void k_hop2_out_final(const u16* __restrict__ outA, const float* __restrict__ out0,
                                                       const float* __restrict__ p_out, const float* __restrict__ scale_out,
                                                       const int* __restrict__ row_start, const int* __restrict__ csr_src,
                                                       float* __restrict__ out){
  int n = blockIdx.x, t = threadIdx.x;
  float sc_ = scale_out[n];
  int beg = row_start[n], end = row_start[n+1];
  int tc = (t < NCLASSC) ? t : 0;
  float a0=0.f,a1=0.f,a2=0.f,a3=0.f;
  int pos = beg;
  for (; pos+4<=end; pos+=4){
    int u0=csr_src[pos], u1=csr_src[pos+1], u2=csr_src[pos+2], u3=csr_src[pos+3];
    float p0=p_out[pos], p1=p_out[pos+1], p2=p_out[pos+2], p3=p_out[pos+3];
    float f0=b2f(outA[(size_t)u0*NCLASSC+tc]);
    float f1=b2f(outA[(size_t)u1*NCLASSC+tc]);
    float f2=b2f(outA[(size_t)u2*NCLASSC+tc]);
    float f3=b2f(outA[(size_t)u3*NCLASSC+tc]);
    a0=fmaf(p0,f0,a0); a1=fmaf(p1,f1,a1); a2=fmaf(p2,f2,a2); a3=fmaf(p3,f3,a3);
  }
  for (; pos<end; pos++){
    a0=fmaf(p_out[pos], b2f(outA[(size_t)csr_src[pos]*NCLASSC+tc]), a0);
  }
  float v = -1e30f;
  if (t < NCLASSC){
    float res = 0.9f*sc_*((a0+a1)+(a2+a3)) + 0.1f*out0[(size_t)n*NCLASSC + t];
    v = res > 0.f ? res : (__expf(res)-1.0f);
  }
  float m = v;
  #pragma unroll
  for (int off=32; off; off>>=1) m = fmaxf(m, __shfl_xor(m, off));
  float ex = (t < NCLASSC) ? __expf(v - m) : 0.f;
  float ssum = ex;
  #pragma unroll
  for (int off=32; off; off>>=1) ssum += __shfl_xor(ssum, off);
  if (t < NCLASSC) out[(size_t)n*NCLASSC + t] = v - m - __logf(ssum);
}

extern "C" void kernel_launch(void* const* d_in, const int* in_sizes, int n_in,
                              void* d_out, int out_size, void* d_ws, size_t ws_size,
                              hipStream_t stream){
  const float* x        = (const float*)d_in[0];
  const int*   ei       = (const int*)d_in[1];
  const float* W        = (const float*)d_in[2];
  const float* a_src    = (const float*)d_in[3];
  const float* a_dst    = (const float*)d_in[4];
  const float* W_out    = (const float*)d_in[5];
  const float* a_src_o  = (const float*)d_in[6];
  const float* a_dst_o  = (const float*)d_in[7];
  float* out            = (float*)d_out;
  const int* e_src = ei;
  const int* e_dst = ei + EE;

  // ---- workspace: ~156.1 MB (< 156.87 MB proven safe in R2) ----
  char* ws = (char*)d_ws;
  size_t off = 0;
  auto alloc = [&](size_t bytes)->char*{ char* p = ws + off; off += (bytes + 255) & ~(size_t)255; return p; };

  u16*    h0        = (u16*)   alloc((size_t)NN*FDIM*2);      // 51.2 MB
  u16*    featA     = (u16*)   alloc((size_t)NN*FDIM*2);      // 51.2 MB (outA aliases after phase 3)
  float*  out0      = (float*) alloc((size_t)NN*NCLASSC*4);   // 16 MB
  int*    csr_src   = (int*)   alloc((size_t)EE*4);           // 6.4 MB
  int*    row_start = (int*)   alloc((size_t)(NN+1)*4);       // 0.4 MB
  char*   regS      =          alloc((size_t)NN*NHEADSC*2*2); // 3.2 MB: s,t then phase-4 smalls
  u16*    p_all     = (u16*)   alloc((size_t)EE*NHEADSC*2);   // 25.6 MB (fp32 p_out aliased later)
  __half* scale     = (__half*)alloc((size_t)NN*NHEADSC*2);   // 1.6 MB
  int*    counts    = (int*)   alloc((size_t)NN*4);           // 0.4 MB
  int*    bsum      = (int*)   alloc((size_t)NBLK*4);
  int*    boff      = (int*)   alloc((size_t)NBLK*4);
  u16*    Wt        = (u16*)   alloc((size_t)FDIM*NFEATC*2);  // 64 KB

  u16*   s         = (u16*)regS;                       // phase 1-3a
  u16*   t_        = (u16*)(regS + (size_t)NN*NHEADSC*2);
  float* s_out     = (float*)regS;                     // phase 4 (s,t dead)
  float* t_out     = s_out + NN;
  float* scale_out = t_out + NN;
  u16*   outA      = (u16*)featA;                      // phase 4 (featA dead)
  float* p_out     = (float*)p_all;                    // phase 4 (p_all dead)

  // phase 1: feature transform (MFMA) + per-head s,t
  k_transposeW<<<(FDIM*NFEATC+255)/256, 256, 0, stream>>>(W, Wt);
  k_gemm1_mfma<<<NN/16, 256, 0, stream>>>(x, Wt, h0);
  k_st<<<(NN*NHEADSC+255)/256, 256, 0, stream>>>(h0, a_src, a_dst, s, t_);

  // phase 2: CSR build (hierarchical scan)
  k_zero<<<(NN+255)/256, 256, 0, stream>>>(counts, NN);
  k_count<<<(EE+255)/256, 256, 0, stream>>>(e_dst, counts);
  k_blocksum<<<NBLK, 256, 0, stream>>>(counts, bsum);
  k_scan_bsum<<<1, 512, 0, stream>>>(bsum, boff);
  k_scan_final<<<NBLK, 256, 0, stream>>>(counts, boff, row_start);
  k_zero<<<(NN+255)/256, 256, 0, stream>>>(counts, NN);
  k_scatter<<<(EE+255)/256, 256, 0, stream>>>(e_src, e_dst, row_start, counts, csr_src);

  // phase 3: attention pass, then full-row hop1 + hop2(+GEMM2)
  k_att<<<(NN*NHEADSC+255)/256, 256, 0, stream>>>(s, t_, row_start, csr_src, p_all, scale);
  k_hop1<<<NN/4, 256, 0, stream>>>(h0, p_all, scale, row_start, csr_src, featA);
  k_hop2<<<NN/4, 256, 0, stream>>>(featA, h0, p_all, scale, row_start, csr_src, W_out, out0);

  // phase 4: output layer (p precomputed fp32, aliased into p_all)
  k_st_out<<<(NN+255)/256, 256, 0, stream>>>(out0, a_src_o, a_dst_o, s_out, t_out);
  k_att_out<<<(NN+255)/256, 256, 0, stream>>>(s_out, t_out, row_start, csr_src, p_out, scale_out);
  k_hop1_out<<<NN, 64, 0, stream>>>(out0, p_out, scale_out, row_start, csr_src, outA);
  k_hop2_out_final<<<NN, 64, 0, stream>>>(outA, out0, p_out, scale_out, row_start, csr_src, out);
}